// Round 7
// baseline (506.492 us; speedup 1.0000x reference)
//
#include <hip/hip_runtime.h>

#define NPTS 4096
#define NQ   8192      // B*N
#define DD   64
#define KNN  16
#define KC   8
#define NSEG 16
#define SEGLEN 256     // NPTS/NSEG (staged knn kernels)
#define FPAD 68        // 67 features + 1 pad (f2 pad slot holds n2; f1 pad = 0)
#define VOFF 1048576   // B*128*N, float offset of v_world in d_out

#define ALWAYS_INLINE __attribute__((always_inline)) inline

__device__ ALWAYS_INLINE float leakyf(float x) { return x > 0.f ? x : 0.1f * x; }

// Pack distance + 12-bit tag into one f32 sort key. d >= 0 always, so float
// compare == uint compare. Truncates mantissa to 11 bits (rel. quantum ~5e-4);
// ties broken by tag (stream-local idx, then pseg) — near-exact lax.top_k.
__device__ ALWAYS_INLINE float packdt(float d, unsigned tag12) {
  return __uint_as_float((__float_as_uint(d) & 0xFFFFF000u) | tag12);
}

// ---- top-k state as NAMED SCALARS (never arrays — hipcc scratch-allocates
// per-thread arrays: rounds 1-4 measured 5-10x slowdown from this) ----
#define TK8_FOREACH(M)  M(0) M(1) M(2) M(3) M(4) M(5) M(6) M(7)
#define TK16_FOREACH(M) M(0) M(1) M(2) M(3) M(4) M(5) M(6) M(7) \
                        M(8) M(9) M(10) M(11) M(12) M(13) M(14) M(15)

// exact (d,i) chain, K=8 — used only on the rigid-regression path
#define TK_DECL1(i) float tkd##i = 3.4e38f; int tki##i = 0;
#define TK_STEP1(i) { bool c = vd < tkd##i; float t_ = tkd##i; int u_ = tki##i; \
                      tkd##i = c ? vd : tkd##i; tki##i = c ? vi : tki##i; \
                      vd = c ? t_ : vd; vi = c ? u_ : vi; }
#define TK8_DECL  TK8_FOREACH(TK_DECL1)
#define TK8_INS(dexp, mexp)  { float vd = (dexp); int vi = (mexp); \
                               if (vd < tkd7)  { TK8_FOREACH(TK_STEP1) } }

// packed min/max chain, K=16: 2 VALU per slot, branchless, no index regs
#define PK_DECL1(i) float pk##i = __uint_as_float(0x7F7FFFFFu);
#define PK_STEP1(i) { float lo_ = fminf(pk##i, pv); pv = fmaxf(pk##i, pv); pk##i = lo_; }
#define PK16_DECL    TK16_FOREACH(PK_DECL1)
#define PK16_INS(ve) { float pv = (ve); TK16_FOREACH(PK_STEP1) }
#define PK_STORE1(i) pdq[i] = pk##i;
#define PK16_STORE   TK16_FOREACH(PK_STORE1)

// ---------------- prep: transposes + weighted features + norms ----------------
__global__ __launch_bounds__(256) void k_prep(
    const float* __restrict__ xyz1, const float* __restrict__ xyz2,
    const float* __restrict__ pts1, const float* __restrict__ pts2,
    const float* __restrict__ w_xyz_p, const float* __restrict__ w_points_p,
    float* __restrict__ f1, float* __restrict__ f2,
    float* __restrict__ n1,
    float* __restrict__ p1t, float* __restrict__ p2t,
    float* __restrict__ x1t, float* __restrict__ x2t)
{
  int gid = blockIdx.x * 256 + threadIdx.x;   // 0..8191
  int b = gid >> 12, n = gid & (NPTS - 1);
  float wx = w_xyz_p[0], wp = w_points_p[0];
  {
    const float* xb = xyz1 + (size_t)b * 3 * NPTS;
    float x = xb[n], y = xb[NPTS + n], z = xb[2 * NPTS + n];
    float nrm2 = fmaf(z, z, fmaf(y, y, x * x));
    float4 xv; xv.x = x; xv.y = y; xv.z = z; xv.w = nrm2;
    *(float4*)&x1t[(size_t)gid * 4] = xv;
    float fx = wx * x, fy = wx * y, fz = wx * z;
    float acc = fmaf(fz, fz, fmaf(fy, fy, fx * fx));
    float* fr = f1 + (size_t)gid * FPAD;
    fr[0] = fx; fr[1] = fy; fr[2] = fz;
    const float* pb = pts1 + (size_t)b * DD * NPTS;
    float* pr = p1t + (size_t)gid * DD;
    for (int c = 0; c < DD; ++c) {
      float v = pb[(size_t)c * NPTS + n];
      pr[c] = v;
      float fv = wp * v;
      fr[3 + c] = fv;
      acc = fmaf(fv, fv, acc);
    }
    fr[67] = 0.f;           // query pad must stay 0 (so pad term adds 0 to dot)
    n1[gid] = acc;
  }
  {
    const float* xb = xyz2 + (size_t)b * 3 * NPTS;
    float x = xb[n], y = xb[NPTS + n], z = xb[2 * NPTS + n];
    float nrm2 = fmaf(z, z, fmaf(y, y, x * x));
    float4 xv; xv.x = x; xv.y = y; xv.z = z; xv.w = nrm2;
    *(float4*)&x2t[(size_t)gid * 4] = xv;
    float fx = wx * x, fy = wx * y, fz = wx * z;
    float acc = fmaf(fz, fz, fmaf(fy, fy, fx * fx));
    float* fr = f2 + (size_t)gid * FPAD;
    fr[0] = fx; fr[1] = fy; fr[2] = fz;
    const float* pb = pts2 + (size_t)b * DD * NPTS;
    float* pr = p2t + (size_t)gid * DD;
    for (int c = 0; c < DD; ++c) {
      float v = pb[(size_t)c * NPTS + n];
      pr[c] = v;
      float fv = wp * v;
      fr[3 + c] = fv;
      acc = fmaf(fv, fv, acc);
    }
    fr[67] = acc;           // candidate pad carries n2
  }
}

// ------- knn over xyz1 (LDS-staged), K=8, EXACT (feeds rigid regression) -------
__global__ __launch_bounds__(256) void k_knn3(
    const float* __restrict__ x4, float* __restrict__ pd, int* __restrict__ pi)
{
  __shared__ __align__(16) float4 sc[128];
  int seg = blockIdx.y;
  int Q = blockIdx.x * 256 + threadIdx.x;
  int b = Q >> 12;
  float4 q = *(const float4*)&x4[(size_t)Q * 4];
  TK8_DECL
  int gbase = (b << 12) + seg * SEGLEN;
  for (int ch = 0; ch < SEGLEN / 128; ++ch) {
    __syncthreads();
    if (threadIdx.x < 128)
      sc[threadIdx.x] = *(const float4*)&x4[(size_t)(gbase + ch * 128 + threadIdx.x) * 4];
    __syncthreads();
    int m0 = seg * SEGLEN + ch * 128;
    for (int j = 0; j < 128; ++j) {
      float4 c = sc[j];
      float dot = fmaf(q.z, c.z, fmaf(q.y, c.y, q.x * c.x));
      float d = fmaxf(q.w + c.w - 2.f * dot, 0.f);
      TK8_INS(d, m0 + j)
    }
  }
  float* pdq = pd + ((size_t)Q * NSEG + seg) * 16;
  int* piq = pi + ((size_t)Q * NSEG + seg) * 16;
#define ST8(i) pdq[i] = tkd##i; piq[i] = tki##i;
  TK8_FOREACH(ST8)
#undef ST8
}

// ------- knn over v_world (LDS-staged), K=16, packed keys -------
__global__ __launch_bounds__(256) void k_knnv(
    const float* __restrict__ x4, float* __restrict__ pd)
{
  __shared__ __align__(16) float4 sc[128];
  int seg = blockIdx.y;
  int Q = blockIdx.x * 256 + threadIdx.x;
  int b = Q >> 12;
  float4 q = *(const float4*)&x4[(size_t)Q * 4];
  PK16_DECL
  int gbase = (b << 12) + seg * SEGLEN;
  for (int ch = 0; ch < SEGLEN / 128; ++ch) {
    __syncthreads();
    if (threadIdx.x < 128)
      sc[threadIdx.x] = *(const float4*)&x4[(size_t)(gbase + ch * 128 + threadIdx.x) * 4];
    __syncthreads();
    unsigned base_tag = ((unsigned)ch << 11) | (unsigned)seg;  // (local<<4)|seg, local=ch*128+j
#pragma unroll
    for (int j = 0; j < 128; ++j) {
      float4 c = sc[j];
      float dot = fmaf(q.z, c.z, fmaf(q.y, c.y, q.x * c.x));
      float d = fmaxf(q.w + c.w - 2.f * dot, 0.f);
      PK16_INS(packdt(d, base_tag | ((unsigned)j << 4)))
    }
  }
  float* pdq = pd + ((size_t)Q * NSEG + seg) * 16;
  PK16_STORE
}

// ---------------- merge K=8 + rigid velocity regression (+ padded v4 out) ----------------
__global__ __launch_bounds__(256) void k_rigid(
    const float* __restrict__ pd, const int* __restrict__ pi,
    const float* __restrict__ x4, const float* __restrict__ vel1,
    float* __restrict__ vout, float* __restrict__ v4out)
{
  int Q = blockIdx.x * 256 + threadIdx.x;
  int b = Q >> 12;
  TK8_DECL
  for (int s = 0; s < NSEG; ++s) {
    const float* pdq = pd + ((size_t)Q * NSEG + s) * 16;
    const int* piq = pi + ((size_t)Q * NSEG + s) * 16;
#pragma unroll
    for (int j = 0; j < KC; ++j) TK8_INS(pdq[j], piq[j])
  }
  int base = b << 12;
  double a00 = 0, a01 = 0, a02 = 0, a11 = 0, a12 = 0, a22 = 0;
  double r0 = 0, r1 = 0, r2 = 0;
#define RIG_ACC(i) { \
    float4 c = *(const float4*)&x4[(size_t)(base + tki##i) * 4]; \
    float nr = sqrtf(c.w); \
    float ux = c.x / nr, uy = c.y / nr, uz = c.z / nr; \
    float cv = vel1[base + tki##i]; \
    double dx = ux, dy = uy, dz = uz, dvv = cv; \
    a00 += dx * dx; a01 += dx * dy; a02 += dx * dz; \
    a11 += dy * dy; a12 += dy * dz; a22 += dz * dz; \
    r0 += dx * dvv; r1 += dy * dvv; r2 += dz * dvv; }
  TK8_FOREACH(RIG_ACC)
#undef RIG_ACC
  a00 += 1e-6; a11 += 1e-6; a22 += 1e-6;
  double c00 = a11 * a22 - a12 * a12;
  double c01 = a02 * a12 - a01 * a22;
  double c02 = a01 * a12 - a02 * a11;
  double c11 = a00 * a22 - a02 * a02;
  double c12 = a02 * a01 - a00 * a12;
  double c22 = a00 * a11 - a01 * a01;
  double det = a00 * c00 + a01 * c01 + a02 * c02;
  double inv = 1.0 / det;
  float vx = (float)((c00 * r0 + c01 * r1 + c02 * r2) * inv);
  float vy = (float)((c01 * r0 + c11 * r1 + c12 * r2) * inv);
  float vz = (float)((c02 * r0 + c12 * r1 + c22 * r2) * inv);
  vout[(size_t)Q * 3 + 0] = vx;
  vout[(size_t)Q * 3 + 1] = vy;
  vout[(size_t)Q * 3 + 2] = vz;
  float4 v; v.x = vx; v.y = vy; v.z = vz;
  v.w = fmaf(vz, vz, fmaf(vy, vy, vx * vx));
  *(float4*)&v4out[(size_t)Q * 4] = v;
}

// ------- knnf: register-tiled distance-GEMM + packed partial top-k -------
// grid (128 q-tiles, 4 segs). sD holds PACKED keys (tag folded in at write).
__global__ __launch_bounds__(256) void k_knnf(
    const float* __restrict__ f1, const float* __restrict__ f2,
    const float* __restrict__ n1,
    float* __restrict__ pd)
{
  __shared__ __align__(16) float4 sf1[64 * 17];   // [q][k4], linear-staged
  __shared__ __align__(16) float4 sf2[64 * 17];   // [c][k4], linear-staged
  __shared__ __align__(16) float  sD[64][68];     // [c][q] packed keys, +4 pad
  int tid = threadIdx.x;
  int tx = tid & 15, ty = tid >> 4;               // c-group, q-group
  int blockq = blockIdx.x * 64;                   // global query base (gid)
  int b = blockq >> 12;
  int seg = blockIdx.y;
  int gbase = (b << 12) + seg * 1024;             // candidate row base (gid)
  const float4* f1v = (const float4*)f1;
  const float4* f2v = (const float4*)f2;
  {
    const float4* src = f1v + (size_t)blockq * 17;
    for (int idx = tid; idx < 1088; idx += 256) sf1[idx] = src[idx];
  }
  float n1q[4];
#pragma unroll
  for (int j = 0; j < 4; ++j) n1q[j] = n1[blockq + ty + 16 * j];
  PK16_DECL
  int p = tid >> 6, qq = tid & 63;
  for (int ch = 0; ch < 16; ++ch) {
    __syncthreads();      // prev chunk's sf2/sD reads complete
    {
      const float4* src = f2v + (size_t)(gbase + ch * 64) * 17;
      for (int idx = tid; idx < 1088; idx += 256) sf2[idx] = src[idx];
    }
    __syncthreads();      // sf2 ready
    float acc[4][4];
#pragma unroll
    for (int j = 0; j < 4; ++j)
#pragma unroll
      for (int i = 0; i < 4; ++i) acc[j][i] = 0.f;
#pragma unroll 4
    for (int k4 = 0; k4 < 16; ++k4) {
      float4 fq[4], fc[4];
#pragma unroll
      for (int j = 0; j < 4; ++j) fq[j] = sf1[(ty + 16 * j) * 17 + k4];
#pragma unroll
      for (int i = 0; i < 4; ++i) fc[i] = sf2[(tx + 16 * i) * 17 + k4];
#pragma unroll
      for (int j = 0; j < 4; ++j)
#pragma unroll
        for (int i = 0; i < 4; ++i) {
          acc[j][i] = fmaf(fq[j].x, fc[i].x, acc[j][i]);
          acc[j][i] = fmaf(fq[j].y, fc[i].y, acc[j][i]);
          acc[j][i] = fmaf(fq[j].z, fc[i].z, acc[j][i]);
          acc[j][i] = fmaf(fq[j].w, fc[i].w, acc[j][i]);
        }
    }
    float cw[4];
    {   // peeled k4 = 16: {f64,f65,f66, n2}; f1 pad .w = 0 so the .w FMA adds 0
      float4 fq[4], fc[4];
#pragma unroll
      for (int j = 0; j < 4; ++j) fq[j] = sf1[(ty + 16 * j) * 17 + 16];
#pragma unroll
      for (int i = 0; i < 4; ++i) { fc[i] = sf2[(tx + 16 * i) * 17 + 16]; cw[i] = fc[i].w; }
#pragma unroll
      for (int j = 0; j < 4; ++j)
#pragma unroll
        for (int i = 0; i < 4; ++i) {
          acc[j][i] = fmaf(fq[j].x, fc[i].x, acc[j][i]);
          acc[j][i] = fmaf(fq[j].y, fc[i].y, acc[j][i]);
          acc[j][i] = fmaf(fq[j].z, fc[i].z, acc[j][i]);
          acc[j][i] = fmaf(fq[j].w, fc[i].w, acc[j][i]);
        }
    }
    // write PACKED keys: candidate c = tx+16i -> local = ch*16+tx (8b), psub = i
    // tag12 = (local<<4) | (seg*4 + i)
#pragma unroll
    for (int i = 0; i < 4; ++i) {
      unsigned tag = (((unsigned)(ch * 16 + tx)) << 4) | (unsigned)(seg * 4 + i);
#pragma unroll
      for (int j = 0; j < 4; ++j) {
        float d = fmaxf(n1q[j] + cw[i] - 2.f * acc[j][i], 0.f);
        sD[tx + 16 * i][ty + 16 * j] = packdt(d, tag);
      }
    }
    __syncthreads();      // sD ready
#pragma unroll
    for (int cl = 0; cl < 16; ++cl)
      PK16_INS(sD[p * 16 + cl][qq])
  }
  int pseg = seg * 4 + p;
  float* pdq = pd + ((size_t)(blockq + qq) * NSEG + pseg) * 16;
  PK16_STORE
}

// ---------------- packed merges: 16 sorted psegs -> top-16, decode global idx ----------------
// MODE 0 (knnf): tag = (local8<<4)|pseg4, local=ch*16+cl, pseg=seg*4+p
//                m = seg*1024 + ch*64 + p*16 + cl
// MODE 1 (knnv): tag = (local8<<4)|seg4, m = seg*256 + local
template<int MODE>
__global__ __launch_bounds__(256) void k_mergepk(
    const float* __restrict__ pd, int* __restrict__ oidx)
{
  int Q = blockIdx.x * 256 + threadIdx.x;
  PK16_DECL
  for (int s = 0; s < NSEG; ++s) {
    const float* pdq = pd + ((size_t)Q * NSEG + s) * 16;
    for (int j = 0; j < 16; ++j) {          // sorted ascending -> early break
      float v = pdq[j];
      if (__all(!(v < pk15))) break;
      PK16_INS(v)
    }
  }
#define DEC(i) { unsigned u = __float_as_uint(pk##i); int m_; \
    if (MODE == 0) { unsigned ps = u & 15u, lo = (u >> 4) & 255u; \
      m_ = (int)(((ps >> 2) << 10) + ((lo >> 4) << 6) + ((ps & 3u) << 4) + (lo & 15u)); } \
    else { m_ = (int)(((u & 15u) << 8) + ((u >> 4) & 255u)); } \
    oidx[(size_t)Q * KNN + i] = m_; }
  TK16_FOREACH(DEC)
#undef DEC
}

// ---------------- fused cost-volume MLP + weightnet1 + k-sum ----------------
// 2 points per block (4096 blocks). Per point: 128 threads = 64 ch-pairs x 2
// k-halves; each thread owns a 2ch x 8k named-scalar accumulator tile so each
// ds_read_b128 feeds 8 FMAs (was 4) -> FMA-bound instead of LDS-bound.
#define MACC8(M) M(0) M(1) M(2) M(3) M(4) M(5) M(6) M(7)
__global__ __launch_bounds__(256) void k_mlp(
    const float* __restrict__ p1t, const float* __restrict__ p2t,
    const float* __restrict__ x1t, const float* __restrict__ x2t,
    const int* __restrict__ kidx,
    const float* __restrict__ W1, const float* __restrict__ B1v,
    const float* __restrict__ W2, const float* __restrict__ B2v,
    const float* __restrict__ wnw1, const float* __restrict__ wnb1,
    const float* __restrict__ wnw2, const float* __restrict__ wnb2,
    const float* __restrict__ wnw3, const float* __restrict__ wnb3,
    float* __restrict__ ptp)
{
  __shared__ __align__(16) float s_p1[2][64];
  __shared__ __align__(16) float s_g2t[2][64][20];
  __shared__ __align__(16) float s_dirt[2][3][20];
  __shared__ __align__(16) float s_h1t[2][128][20];
  __shared__ __align__(16) float s_wn[2][16][8];
  __shared__ __align__(16) float s_red[2][2][128];
  int tid = threadIdx.x;
  int pt = tid >> 7, lo = tid & 127;
  int gid = blockIdx.x * 2 + pt, b = gid >> 12;
  int c2 = (lo & 63) * 2, kh = lo >> 6, kb = kh * 8;

  if (lo < 16) {
    ((float4*)s_p1[pt])[lo] = *(const float4*)&p1t[(size_t)gid * 64 + lo * 4];
    int m = kidx[(size_t)gid * 16 + lo];
    int grow = (b << 12) + m;
    float4 cx2 = *(const float4*)&x2t[(size_t)grow * 4];
    float4 cx1 = *(const float4*)&x1t[(size_t)gid * 4];
    s_dirt[pt][0][lo] = cx2.x - cx1.x;
    s_dirt[pt][1][lo] = cx2.y - cx1.y;
    s_dirt[pt][2][lo] = cx2.z - cx1.z;
  }
  for (int idx = lo; idx < 256; idx += 128) {
    int k_ld = idx >> 4, c_ld = (idx & 15) * 4;
    int m = kidx[(size_t)gid * 16 + k_ld];
    int grow = (b << 12) + m;
    float4 gv = *(const float4*)&p2t[(size_t)grow * 64 + c_ld];
    s_g2t[pt][c_ld + 0][k_ld] = gv.x;
    s_g2t[pt][c_ld + 1][k_ld] = gv.y;
    s_g2t[pt][c_ld + 2][k_ld] = gv.z;
    s_g2t[pt][c_ld + 3][k_ld] = gv.w;
  }
  __syncthreads();
  if (lo < 16) {
    float dx = s_dirt[pt][0][lo], dy = s_dirt[pt][1][lo], dz = s_dirt[pt][2][lo];
    float h0_ = fmaxf(fmaf(dz, wnw1[16 + 0], fmaf(dy, wnw1[8 + 0], fmaf(dx, wnw1[0], wnb1[0]))), 0.f);
    float h1_ = fmaxf(fmaf(dz, wnw1[16 + 1], fmaf(dy, wnw1[8 + 1], fmaf(dx, wnw1[1], wnb1[1]))), 0.f);
    float h2_ = fmaxf(fmaf(dz, wnw1[16 + 2], fmaf(dy, wnw1[8 + 2], fmaf(dx, wnw1[2], wnb1[2]))), 0.f);
    float h3_ = fmaxf(fmaf(dz, wnw1[16 + 3], fmaf(dy, wnw1[8 + 3], fmaf(dx, wnw1[3], wnb1[3]))), 0.f);
    float h4_ = fmaxf(fmaf(dz, wnw1[16 + 4], fmaf(dy, wnw1[8 + 4], fmaf(dx, wnw1[4], wnb1[4]))), 0.f);
    float h5_ = fmaxf(fmaf(dz, wnw1[16 + 5], fmaf(dy, wnw1[8 + 5], fmaf(dx, wnw1[5], wnb1[5]))), 0.f);
    float h6_ = fmaxf(fmaf(dz, wnw1[16 + 6], fmaf(dy, wnw1[8 + 6], fmaf(dx, wnw1[6], wnb1[6]))), 0.f);
    float h7_ = fmaxf(fmaf(dz, wnw1[16 + 7], fmaf(dy, wnw1[8 + 7], fmaf(dx, wnw1[7], wnb1[7]))), 0.f);
#pragma unroll
    for (int j = 0; j < 8; ++j) {
      float a = wnb2[j];
      a = fmaf(h0_, wnw2[0 * 8 + j], a); a = fmaf(h1_, wnw2[1 * 8 + j], a);
      a = fmaf(h2_, wnw2[2 * 8 + j], a); a = fmaf(h3_, wnw2[3 * 8 + j], a);
      a = fmaf(h4_, wnw2[4 * 8 + j], a); a = fmaf(h5_, wnw2[5 * 8 + j], a);
      a = fmaf(h6_, wnw2[6 * 8 + j], a); a = fmaf(h7_, wnw2[7 * 8 + j], a);
      s_wn[pt][lo][j] = fmaxf(a, 0.f);
    }
  }
  // layer1: p1-center partial (k-invariant) for 2 channels
  float2 b1 = *(const float2*)&B1v[c2];
  float pre0 = b1.x, pre1 = b1.y;
#pragma unroll 4
  for (int c4 = 0; c4 < 16; ++c4) {
    float4 p = ((float4*)s_p1[pt])[c4];
    const float* wr = &W1[(size_t)c4 * 4 * 128 + c2];
    float2 wa = *(const float2*)&wr[0];
    float2 wb = *(const float2*)&wr[128];
    float2 wc = *(const float2*)&wr[256];
    float2 wd = *(const float2*)&wr[384];
    pre0 = fmaf(p.x, wa.x, pre0); pre1 = fmaf(p.x, wa.y, pre1);
    pre0 = fmaf(p.y, wb.x, pre0); pre1 = fmaf(p.y, wb.y, pre1);
    pre0 = fmaf(p.z, wc.x, pre0); pre1 = fmaf(p.z, wc.y, pre1);
    pre0 = fmaf(p.w, wd.x, pre0); pre1 = fmaf(p.w, wd.y, pre1);
  }
#define DECL_A(j) float a0##j = pre0; float a1##j = pre1;
  MACC8(DECL_A)
#undef DECL_A
  for (int c = 0; c < 64; ++c) {
    float4 g0 = *(const float4*)&s_g2t[pt][c][kb];
    float4 g1 = *(const float4*)&s_g2t[pt][c][kb + 4];
    float2 w = *(const float2*)&W1[(size_t)(64 + c) * 128 + c2];
    a00 = fmaf(g0.x, w.x, a00); a10 = fmaf(g0.x, w.y, a10);
    a01 = fmaf(g0.y, w.x, a01); a11 = fmaf(g0.y, w.y, a11);
    a02 = fmaf(g0.z, w.x, a02); a12 = fmaf(g0.z, w.y, a12);
    a03 = fmaf(g0.w, w.x, a03); a13 = fmaf(g0.w, w.y, a13);
    a04 = fmaf(g1.x, w.x, a04); a14 = fmaf(g1.x, w.y, a14);
    a05 = fmaf(g1.y, w.x, a05); a15 = fmaf(g1.y, w.y, a15);
    a06 = fmaf(g1.z, w.x, a06); a16 = fmaf(g1.z, w.y, a16);
    a07 = fmaf(g1.w, w.x, a07); a17 = fmaf(g1.w, w.y, a17);
  }
#pragma unroll
  for (int jd = 0; jd < 3; ++jd) {
    float4 d0 = *(const float4*)&s_dirt[pt][jd][kb];
    float4 d1 = *(const float4*)&s_dirt[pt][jd][kb + 4];
    float2 w = *(const float2*)&W1[(size_t)(128 + jd) * 128 + c2];
    a00 = fmaf(d0.x, w.x, a00); a10 = fmaf(d0.x, w.y, a10);
    a01 = fmaf(d0.y, w.x, a01); a11 = fmaf(d0.y, w.y, a11);
    a02 = fmaf(d0.z, w.x, a02); a12 = fmaf(d0.z, w.y, a12);
    a03 = fmaf(d0.w, w.x, a03); a13 = fmaf(d0.w, w.y, a13);
    a04 = fmaf(d1.x, w.x, a04); a14 = fmaf(d1.x, w.y, a14);
    a05 = fmaf(d1.y, w.x, a05); a15 = fmaf(d1.y, w.y, a15);
    a06 = fmaf(d1.z, w.x, a06); a16 = fmaf(d1.z, w.y, a16);
    a07 = fmaf(d1.w, w.x, a07); a17 = fmaf(d1.w, w.y, a17);
  }
  {
    float4 h;
    h.x = leakyf(a00); h.y = leakyf(a01); h.z = leakyf(a02); h.w = leakyf(a03);
    *(float4*)&s_h1t[pt][c2][kb] = h;
    h.x = leakyf(a04); h.y = leakyf(a05); h.z = leakyf(a06); h.w = leakyf(a07);
    *(float4*)&s_h1t[pt][c2][kb + 4] = h;
    h.x = leakyf(a10); h.y = leakyf(a11); h.z = leakyf(a12); h.w = leakyf(a13);
    *(float4*)&s_h1t[pt][c2 + 1][kb] = h;
    h.x = leakyf(a14); h.y = leakyf(a15); h.z = leakyf(a16); h.w = leakyf(a17);
    *(float4*)&s_h1t[pt][c2 + 1][kb + 4] = h;
  }
  __syncthreads();
  float2 b2v = *(const float2*)&B2v[c2];
#define DECL_Q(j) float q0##j = b2v.x; float q1##j = b2v.y;
  MACC8(DECL_Q)
#undef DECL_Q
  for (int c = 0; c < 128; ++c) {
    float4 h0 = *(const float4*)&s_h1t[pt][c][kb];
    float4 h1 = *(const float4*)&s_h1t[pt][c][kb + 4];
    float2 w = *(const float2*)&W2[(size_t)c * 128 + c2];
    q00 = fmaf(h0.x, w.x, q00); q10 = fmaf(h0.x, w.y, q10);
    q01 = fmaf(h0.y, w.x, q01); q11 = fmaf(h0.y, w.y, q11);
    q02 = fmaf(h0.z, w.x, q02); q12 = fmaf(h0.z, w.y, q12);
    q03 = fmaf(h0.w, w.x, q03); q13 = fmaf(h0.w, w.y, q13);
    q04 = fmaf(h1.x, w.x, q04); q14 = fmaf(h1.x, w.y, q14);
    q05 = fmaf(h1.y, w.x, q05); q15 = fmaf(h1.y, w.y, q15);
    q06 = fmaf(h1.z, w.x, q06); q16 = fmaf(h1.z, w.y, q16);
    q07 = fmaf(h1.w, w.x, q07); q17 = fmaf(h1.w, w.y, q17);
  }
  // weightnet1 layer-3 column weights for the 2 channels (k-invariant: hoisted)
  float2 w3_0 = *(const float2*)&wnw3[0 * 128 + c2];
  float2 w3_1 = *(const float2*)&wnw3[1 * 128 + c2];
  float2 w3_2 = *(const float2*)&wnw3[2 * 128 + c2];
  float2 w3_3 = *(const float2*)&wnw3[3 * 128 + c2];
  float2 w3_4 = *(const float2*)&wnw3[4 * 128 + c2];
  float2 w3_5 = *(const float2*)&wnw3[5 * 128 + c2];
  float2 w3_6 = *(const float2*)&wnw3[6 * 128 + c2];
  float2 w3_7 = *(const float2*)&wnw3[7 * 128 + c2];
  float2 b3 = *(const float2*)&wnb3[c2];
  float r0 = 0.f, r1 = 0.f;
#define FINK(j) { \
    int k_ = kb + j; \
    float4 wa = *(const float4*)&s_wn[pt][k_][0]; \
    float4 wb = *(const float4*)&s_wn[pt][k_][4]; \
    float wv0 = b3.x, wv1 = b3.y; \
    wv0 = fmaf(wa.x, w3_0.x, wv0); wv1 = fmaf(wa.x, w3_0.y, wv1); \
    wv0 = fmaf(wa.y, w3_1.x, wv0); wv1 = fmaf(wa.y, w3_1.y, wv1); \
    wv0 = fmaf(wa.z, w3_2.x, wv0); wv1 = fmaf(wa.z, w3_2.y, wv1); \
    wv0 = fmaf(wa.w, w3_3.x, wv0); wv1 = fmaf(wa.w, w3_3.y, wv1); \
    wv0 = fmaf(wb.x, w3_4.x, wv0); wv1 = fmaf(wb.x, w3_4.y, wv1); \
    wv0 = fmaf(wb.y, w3_5.x, wv0); wv1 = fmaf(wb.y, w3_5.y, wv1); \
    wv0 = fmaf(wb.z, w3_6.x, wv0); wv1 = fmaf(wb.z, w3_6.y, wv1); \
    wv0 = fmaf(wb.w, w3_7.x, wv0); wv1 = fmaf(wb.w, w3_7.y, wv1); \
    wv0 = fmaxf(wv0, 0.f); wv1 = fmaxf(wv1, 0.f); \
    r0 = fmaf(wv0, leakyf(q0##j), r0); r1 = fmaf(wv1, leakyf(q1##j), r1); }
  MACC8(FINK)
#undef FINK
  s_red[pt][kh][c2] = r0;
  s_red[pt][kh][c2 + 1] = r1;
  __syncthreads();
  if (kh == 0) {
    float2 o;
    o.x = s_red[pt][0][c2] + s_red[pt][1][c2];
    o.y = s_red[pt][0][c2 + 1] + s_red[pt][1][c2 + 1];
    *(float2*)&ptp[(size_t)gid * 128 + c2] = o;
  }
}

// ---------------- final: weightnet2 + gather + k-sum + transpose store ----------------
__global__ __launch_bounds__(256) void k_final(
    const float* __restrict__ x1t, const int* __restrict__ idx2,
    const float* __restrict__ ptp,
    const float* __restrict__ wnw1, const float* __restrict__ wnb1,
    const float* __restrict__ wnw2, const float* __restrict__ wnb2,
    const float* __restrict__ wnw3, const float* __restrict__ wnb3,
    float* __restrict__ out0)
{
  __shared__ __align__(16) float s_gc[16][128];
  __shared__ __align__(16) float s_wn[16][8];
  __shared__ __align__(16) float s_red[2][128];
  int gid = blockIdx.x, b = gid >> 12, n = gid & (NPTS - 1);
  int tid = threadIdx.x;
  if (tid < 16) {
    int m = idx2[(size_t)gid * 16 + tid];
    float4 c2 = *(const float4*)&x1t[(size_t)((b << 12) + m) * 4];
    float4 c1 = *(const float4*)&x1t[(size_t)gid * 4];
    float dx = c2.x - c1.x, dy = c2.y - c1.y, dz = c2.z - c1.z;
    float h1w[8];
#pragma unroll
    for (int j = 0; j < 8; ++j)
      h1w[j] = fmaxf(fmaf(dz, wnw1[16 + j], fmaf(dy, wnw1[8 + j], fmaf(dx, wnw1[j], wnb1[j]))), 0.f);
#pragma unroll
    for (int j = 0; j < 8; ++j) {
      float a = wnb2[j];
#pragma unroll
      for (int qq = 0; qq < 8; ++qq) a = fmaf(h1w[qq], wnw2[qq * 8 + j], a);
      s_wn[tid][j] = fmaxf(a, 0.f);
    }
  }
  int k2 = tid >> 4, i2 = tid & 15;
  int mg = idx2[(size_t)gid * 16 + k2];
  const float* src = &ptp[(size_t)((b << 12) + mg) * 128 + i2 * 8];
  *(float4*)&s_gc[k2][i2 * 8] = *(const float4*)&src[0];
  *(float4*)&s_gc[k2][i2 * 8 + 4] = *(const float4*)&src[4];
  __syncthreads();
  int ch = tid & 127, kg2 = tid >> 7;
  float r = 0.f;
#pragma unroll
  for (int jj = 0; jj < 8; ++jj) {
    int k = kg2 * 8 + jj;
    float4 wa = *(const float4*)&s_wn[k][0];
    float4 wb = *(const float4*)&s_wn[k][4];
    float wv = wnb3[ch];
    wv = fmaf(wa.x, wnw3[ch], wv);
    wv = fmaf(wa.y, wnw3[128 + ch], wv);
    wv = fmaf(wa.z, wnw3[256 + ch], wv);
    wv = fmaf(wa.w, wnw3[384 + ch], wv);
    wv = fmaf(wb.x, wnw3[512 + ch], wv);
    wv = fmaf(wb.y, wnw3[640 + ch], wv);
    wv = fmaf(wb.z, wnw3[768 + ch], wv);
    wv = fmaf(wb.w, wnw3[896 + ch], wv);
    wv = fmaxf(wv, 0.f);
    r = fmaf(wv, s_gc[k][ch], r);
  }
  s_red[kg2][ch] = r;
  __syncthreads();
  if (tid < 128)
    out0[(size_t)(b * 128 + tid) * NPTS + n] = s_red[0][tid] + s_red[1][tid];
}

extern "C" void kernel_launch(void* const* d_in, const int* in_sizes, int n_in,
                              void* d_out, int out_size, void* d_ws, size_t ws_size,
                              hipStream_t stream) {
  (void)in_sizes; (void)n_in; (void)out_size; (void)ws_size;
  const float* xyz1   = (const float*)d_in[0];
  const float* xyz2   = (const float*)d_in[1];
  const float* pts1   = (const float*)d_in[2];
  const float* pts2   = (const float*)d_in[3];
  const float* vel1   = (const float*)d_in[4];
  const float* w_xyz  = (const float*)d_in[8];
  const float* w_pts  = (const float*)d_in[10];
  const float* mlp_w1 = (const float*)d_in[11];
  const float* mlp_b1 = (const float*)d_in[12];
  const float* mlp_w2 = (const float*)d_in[13];
  const float* mlp_b2 = (const float*)d_in[14];
  const float* wn1_w1 = (const float*)d_in[15];
  const float* wn1_b1 = (const float*)d_in[16];
  const float* wn1_w2 = (const float*)d_in[17];
  const float* wn1_b2 = (const float*)d_in[18];
  const float* wn1_w3 = (const float*)d_in[19];
  const float* wn1_b3 = (const float*)d_in[20];
  const float* wn2_w1 = (const float*)d_in[21];
  const float* wn2_b1 = (const float*)d_in[22];
  const float* wn2_w2 = (const float*)d_in[23];
  const float* wn2_b2 = (const float*)d_in[24];
  const float* wn2_w3 = (const float*)d_in[25];
  const float* wn2_b3 = (const float*)d_in[26];

  char* ws = (char*)d_ws;
  size_t off = 0;
  float* pd   = (float*)(ws + off); off += (size_t)NQ * NSEG * 16 * 4;   // 8 MB
  int*   pi   = (int*)(ws + off);   off += (size_t)NQ * NSEG * 16 * 4;   // 8 MB
  float* f1   = (float*)(ws + off); off += (size_t)NQ * FPAD * 4;
  float* f2   = (float*)(ws + off); off += (size_t)NQ * FPAD * 4;
  float* n1   = (float*)(ws + off); off += (size_t)NQ * 4;
  float* p1t  = (float*)(ws + off); off += (size_t)NQ * DD * 4;
  float* p2t  = (float*)(ws + off); off += (size_t)NQ * DD * 4;
  float* x1t  = (float*)(ws + off); off += (size_t)NQ * 4 * 4;
  float* x2t  = (float*)(ws + off); off += (size_t)NQ * 4 * 4;
  int*   kidx = (int*)(ws + off);   off += (size_t)NQ * KNN * 4;
  float* ptp  = (float*)(ws + off); off += (size_t)NQ * 128 * 4;
  int*   idx2 = (int*)(ws + off);   off += (size_t)NQ * KNN * 4;
  float* v4   = (float*)(ws + off); off += (size_t)NQ * 4 * 4;

  float* out0 = (float*)d_out;
  float* outv = (float*)d_out + VOFF;

  k_prep<<<32, 256, 0, stream>>>(xyz1, xyz2, pts1, pts2, w_xyz, w_pts,
                                 f1, f2, n1, p1t, p2t, x1t, x2t);
  k_knn3<<<dim3(32, NSEG), 256, 0, stream>>>(x1t, pd, pi);
  k_rigid<<<32, 256, 0, stream>>>(pd, pi, x1t, vel1, outv, v4);
  k_knnf<<<dim3(128, 4), 256, 0, stream>>>(f1, f2, n1, pd);
  k_mergepk<0><<<32, 256, 0, stream>>>(pd, kidx);
  k_mlp<<<NQ / 2, 256, 0, stream>>>(p1t, p2t, x1t, x2t, kidx,
                                    mlp_w1, mlp_b1, mlp_w2, mlp_b2,
                                    wn1_w1, wn1_b1, wn1_w2, wn1_b2, wn1_w3, wn1_b3, ptp);
  k_knnv<<<dim3(32, NSEG), 256, 0, stream>>>(v4, pd);
  k_mergepk<1><<<32, 256, 0, stream>>>(pd, idx2);
  k_final<<<NQ, 256, 0, stream>>>(x1t, idx2, ptp,
                                  wn2_w1, wn2_b1, wn2_w2, wn2_b2, wn2_w3, wn2_b3, out0);
}

// Round 8
// 425.227 us; speedup vs baseline: 1.1911x; 1.1911x over previous
//
#include <hip/hip_runtime.h>

#define NPTS 4096
#define NQ   8192      // B*N
#define DD   64
#define KNN  16
#define KC   8
#define NSEG 16
#define SEGLEN 256     // NPTS/NSEG (staged knn kernels)
#define FPAD 68        // 67 features + 1 pad (f2 pad slot holds n2; f1 pad = 0)
#define VOFF 1048576   // B*128*N, float offset of v_world in d_out

#define ALWAYS_INLINE __attribute__((always_inline)) inline

typedef __attribute__((ext_vector_type(8))) short bf16x8;
typedef __attribute__((ext_vector_type(4))) float f32x4;

__device__ ALWAYS_INLINE float leakyf(float x) { return x > 0.f ? x : 0.1f * x; }

__device__ ALWAYS_INLINE unsigned short bf16rne(float f) {
  unsigned u = __float_as_uint(f);
  u = (u + 0x7FFFu + ((u >> 16) & 1u)) >> 16;
  return (unsigned short)u;
}

// Pack distance + 12-bit tag into one f32 sort key (d>=0 so float cmp == uint cmp).
__device__ ALWAYS_INLINE float packdt(float d, unsigned tag12) {
  return __uint_as_float((__float_as_uint(d) & 0xFFFFF000u) | tag12);
}

// ---- top-k state as NAMED SCALARS (never arrays — hipcc scratch-allocates
// per-thread arrays: rounds 1-4 measured 5-10x slowdown from this) ----
#define TK8_FOREACH(M)  M(0) M(1) M(2) M(3) M(4) M(5) M(6) M(7)
#define TK16_FOREACH(M) M(0) M(1) M(2) M(3) M(4) M(5) M(6) M(7) \
                        M(8) M(9) M(10) M(11) M(12) M(13) M(14) M(15)

#define TK_DECL1(i) float tkd##i = 3.4e38f; int tki##i = 0;
#define TK_STEP1(i) { bool c = vd < tkd##i; float t_ = tkd##i; int u_ = tki##i; \
                      tkd##i = c ? vd : tkd##i; tki##i = c ? vi : tki##i; \
                      vd = c ? t_ : vd; vi = c ? u_ : vi; }
#define TK8_DECL  TK8_FOREACH(TK_DECL1)
#define TK8_INS(dexp, mexp)  { float vd = (dexp); int vi = (mexp); \
                               if (vd < tkd7)  { TK8_FOREACH(TK_STEP1) } }

#define PK_DECL1(i) float pk##i = __uint_as_float(0x7F7FFFFFu);
#define PK_STEP1(i) { float lo_ = fminf(pk##i, pv); pv = fmaxf(pk##i, pv); pk##i = lo_; }
#define PK16_DECL    TK16_FOREACH(PK_DECL1)
#define PK16_INS(ve) { float pv = (ve); TK16_FOREACH(PK_STEP1) }
#define PK_STORE1(i) pdq[i] = pk##i;
#define PK16_STORE   TK16_FOREACH(PK_STORE1)

// ---------------- prep: transposes + weighted features + norms ----------------
__global__ __launch_bounds__(256) void k_prep(
    const float* __restrict__ xyz1, const float* __restrict__ xyz2,
    const float* __restrict__ pts1, const float* __restrict__ pts2,
    const float* __restrict__ w_xyz_p, const float* __restrict__ w_points_p,
    float* __restrict__ f1, float* __restrict__ f2,
    float* __restrict__ n1,
    float* __restrict__ p1t, float* __restrict__ p2t,
    float* __restrict__ x1t, float* __restrict__ x2t)
{
  int gid = blockIdx.x * 256 + threadIdx.x;   // 0..8191
  int b = gid >> 12, n = gid & (NPTS - 1);
  float wx = w_xyz_p[0], wp = w_points_p[0];
  {
    const float* xb = xyz1 + (size_t)b * 3 * NPTS;
    float x = xb[n], y = xb[NPTS + n], z = xb[2 * NPTS + n];
    float nrm2 = fmaf(z, z, fmaf(y, y, x * x));
    float4 xv; xv.x = x; xv.y = y; xv.z = z; xv.w = nrm2;
    *(float4*)&x1t[(size_t)gid * 4] = xv;
    float fx = wx * x, fy = wx * y, fz = wx * z;
    float acc = fmaf(fz, fz, fmaf(fy, fy, fx * fx));
    float* fr = f1 + (size_t)gid * FPAD;
    fr[0] = fx; fr[1] = fy; fr[2] = fz;
    const float* pb = pts1 + (size_t)b * DD * NPTS;
    float* pr = p1t + (size_t)gid * DD;
    for (int c = 0; c < DD; ++c) {
      float v = pb[(size_t)c * NPTS + n];
      pr[c] = v;
      float fv = wp * v;
      fr[3 + c] = fv;
      acc = fmaf(fv, fv, acc);
    }
    fr[67] = 0.f;
    n1[gid] = acc;
  }
  {
    const float* xb = xyz2 + (size_t)b * 3 * NPTS;
    float x = xb[n], y = xb[NPTS + n], z = xb[2 * NPTS + n];
    float nrm2 = fmaf(z, z, fmaf(y, y, x * x));
    float4 xv; xv.x = x; xv.y = y; xv.z = z; xv.w = nrm2;
    *(float4*)&x2t[(size_t)gid * 4] = xv;
    float fx = wx * x, fy = wx * y, fz = wx * z;
    float acc = fmaf(fz, fz, fmaf(fy, fy, fx * fx));
    float* fr = f2 + (size_t)gid * FPAD;
    fr[0] = fx; fr[1] = fy; fr[2] = fz;
    const float* pb = pts2 + (size_t)b * DD * NPTS;
    float* pr = p2t + (size_t)gid * DD;
    for (int c = 0; c < DD; ++c) {
      float v = pb[(size_t)c * NPTS + n];
      pr[c] = v;
      float fv = wp * v;
      fr[3 + c] = fv;
      acc = fmaf(fv, fv, acc);
    }
    fr[67] = acc;
  }
}

// ------- knn over xyz1 (LDS-staged), K=8, EXACT (feeds rigid regression) -------
__global__ __launch_bounds__(256) void k_knn3(
    const float* __restrict__ x4, float* __restrict__ pd, int* __restrict__ pi)
{
  __shared__ __align__(16) float4 sc[128];
  int seg = blockIdx.y;
  int Q = blockIdx.x * 256 + threadIdx.x;
  int b = Q >> 12;
  float4 q = *(const float4*)&x4[(size_t)Q * 4];
  TK8_DECL
  int gbase = (b << 12) + seg * SEGLEN;
  for (int ch = 0; ch < SEGLEN / 128; ++ch) {
    __syncthreads();
    if (threadIdx.x < 128)
      sc[threadIdx.x] = *(const float4*)&x4[(size_t)(gbase + ch * 128 + threadIdx.x) * 4];
    __syncthreads();
    int m0 = seg * SEGLEN + ch * 128;
    for (int j = 0; j < 128; ++j) {
      float4 c = sc[j];
      float dot = fmaf(q.z, c.z, fmaf(q.y, c.y, q.x * c.x));
      float d = fmaxf(q.w + c.w - 2.f * dot, 0.f);
      TK8_INS(d, m0 + j)
    }
  }
  float* pdq = pd + ((size_t)Q * NSEG + seg) * 16;
  int* piq = pi + ((size_t)Q * NSEG + seg) * 16;
#define ST8(i) pdq[i] = tkd##i; piq[i] = tki##i;
  TK8_FOREACH(ST8)
#undef ST8
}

// ------- knn over v_world (LDS-staged), K=16, packed keys -------
__global__ __launch_bounds__(256) void k_knnv(
    const float* __restrict__ x4, float* __restrict__ pd)
{
  __shared__ __align__(16) float4 sc[128];
  int seg = blockIdx.y;
  int Q = blockIdx.x * 256 + threadIdx.x;
  int b = Q >> 12;
  float4 q = *(const float4*)&x4[(size_t)Q * 4];
  PK16_DECL
  int gbase = (b << 12) + seg * SEGLEN;
  for (int ch = 0; ch < SEGLEN / 128; ++ch) {
    __syncthreads();
    if (threadIdx.x < 128)
      sc[threadIdx.x] = *(const float4*)&x4[(size_t)(gbase + ch * 128 + threadIdx.x) * 4];
    __syncthreads();
    unsigned base_tag = ((unsigned)ch << 11) | (unsigned)seg;
#pragma unroll
    for (int j = 0; j < 128; ++j) {
      float4 c = sc[j];
      float dot = fmaf(q.z, c.z, fmaf(q.y, c.y, q.x * c.x));
      float d = fmaxf(q.w + c.w - 2.f * dot, 0.f);
      PK16_INS(packdt(d, base_tag | ((unsigned)j << 4)))
    }
  }
  float* pdq = pd + ((size_t)Q * NSEG + seg) * 16;
  PK16_STORE
}

// ---------------- merge K=8 + rigid velocity regression (+ padded v4 out) ----------------
__global__ __launch_bounds__(256) void k_rigid(
    const float* __restrict__ pd, const int* __restrict__ pi,
    const float* __restrict__ x4, const float* __restrict__ vel1,
    float* __restrict__ vout, float* __restrict__ v4out)
{
  int Q = blockIdx.x * 256 + threadIdx.x;
  int b = Q >> 12;
  TK8_DECL
  for (int s = 0; s < NSEG; ++s) {
    const float* pdq = pd + ((size_t)Q * NSEG + s) * 16;
    const int* piq = pi + ((size_t)Q * NSEG + s) * 16;
#pragma unroll
    for (int j = 0; j < KC; ++j) TK8_INS(pdq[j], piq[j])
  }
  int base = b << 12;
  double a00 = 0, a01 = 0, a02 = 0, a11 = 0, a12 = 0, a22 = 0;
  double r0 = 0, r1 = 0, r2 = 0;
#define RIG_ACC(i) { \
    float4 c = *(const float4*)&x4[(size_t)(base + tki##i) * 4]; \
    float nr = sqrtf(c.w); \
    float ux = c.x / nr, uy = c.y / nr, uz = c.z / nr; \
    float cv = vel1[base + tki##i]; \
    double dx = ux, dy = uy, dz = uz, dvv = cv; \
    a00 += dx * dx; a01 += dx * dy; a02 += dx * dz; \
    a11 += dy * dy; a12 += dy * dz; a22 += dz * dz; \
    r0 += dx * dvv; r1 += dy * dvv; r2 += dz * dvv; }
  TK8_FOREACH(RIG_ACC)
#undef RIG_ACC
  a00 += 1e-6; a11 += 1e-6; a22 += 1e-6;
  double c00 = a11 * a22 - a12 * a12;
  double c01 = a02 * a12 - a01 * a22;
  double c02 = a01 * a12 - a02 * a11;
  double c11 = a00 * a22 - a02 * a02;
  double c12 = a02 * a01 - a00 * a12;
  double c22 = a00 * a11 - a01 * a01;
  double det = a00 * c00 + a01 * c01 + a02 * c02;
  double inv = 1.0 / det;
  float vx = (float)((c00 * r0 + c01 * r1 + c02 * r2) * inv);
  float vy = (float)((c01 * r0 + c11 * r1 + c12 * r2) * inv);
  float vz = (float)((c02 * r0 + c12 * r1 + c22 * r2) * inv);
  vout[(size_t)Q * 3 + 0] = vx;
  vout[(size_t)Q * 3 + 1] = vy;
  vout[(size_t)Q * 3 + 2] = vz;
  float4 v; v.x = vx; v.y = vy; v.z = vz;
  v.w = fmaf(vz, vz, fmaf(vy, vy, vx * vx));
  *(float4*)&v4out[(size_t)Q * 4] = v;
}

// ------- knnf: register-tiled distance-GEMM + packed partial top-k -------
__global__ __launch_bounds__(256) void k_knnf(
    const float* __restrict__ f1, const float* __restrict__ f2,
    const float* __restrict__ n1,
    float* __restrict__ pd)
{
  __shared__ __align__(16) float4 sf1[64 * 17];
  __shared__ __align__(16) float4 sf2[64 * 17];
  __shared__ __align__(16) float  sD[64][68];
  int tid = threadIdx.x;
  int tx = tid & 15, ty = tid >> 4;
  int blockq = blockIdx.x * 64;
  int b = blockq >> 12;
  int seg = blockIdx.y;
  int gbase = (b << 12) + seg * 1024;
  const float4* f1v = (const float4*)f1;
  const float4* f2v = (const float4*)f2;
  {
    const float4* src = f1v + (size_t)blockq * 17;
    for (int idx = tid; idx < 1088; idx += 256) sf1[idx] = src[idx];
  }
  float n1q[4];
#pragma unroll
  for (int j = 0; j < 4; ++j) n1q[j] = n1[blockq + ty + 16 * j];
  PK16_DECL
  int p = tid >> 6, qq = tid & 63;
  for (int ch = 0; ch < 16; ++ch) {
    __syncthreads();
    {
      const float4* src = f2v + (size_t)(gbase + ch * 64) * 17;
      for (int idx = tid; idx < 1088; idx += 256) sf2[idx] = src[idx];
    }
    __syncthreads();
    float acc[4][4];
#pragma unroll
    for (int j = 0; j < 4; ++j)
#pragma unroll
      for (int i = 0; i < 4; ++i) acc[j][i] = 0.f;
#pragma unroll 4
    for (int k4 = 0; k4 < 16; ++k4) {
      float4 fq[4], fc[4];
#pragma unroll
      for (int j = 0; j < 4; ++j) fq[j] = sf1[(ty + 16 * j) * 17 + k4];
#pragma unroll
      for (int i = 0; i < 4; ++i) fc[i] = sf2[(tx + 16 * i) * 17 + k4];
#pragma unroll
      for (int j = 0; j < 4; ++j)
#pragma unroll
        for (int i = 0; i < 4; ++i) {
          acc[j][i] = fmaf(fq[j].x, fc[i].x, acc[j][i]);
          acc[j][i] = fmaf(fq[j].y, fc[i].y, acc[j][i]);
          acc[j][i] = fmaf(fq[j].z, fc[i].z, acc[j][i]);
          acc[j][i] = fmaf(fq[j].w, fc[i].w, acc[j][i]);
        }
    }
    float cw[4];
    {
      float4 fq[4], fc[4];
#pragma unroll
      for (int j = 0; j < 4; ++j) fq[j] = sf1[(ty + 16 * j) * 17 + 16];
#pragma unroll
      for (int i = 0; i < 4; ++i) { fc[i] = sf2[(tx + 16 * i) * 17 + 16]; cw[i] = fc[i].w; }
#pragma unroll
      for (int j = 0; j < 4; ++j)
#pragma unroll
        for (int i = 0; i < 4; ++i) {
          acc[j][i] = fmaf(fq[j].x, fc[i].x, acc[j][i]);
          acc[j][i] = fmaf(fq[j].y, fc[i].y, acc[j][i]);
          acc[j][i] = fmaf(fq[j].z, fc[i].z, acc[j][i]);
          acc[j][i] = fmaf(fq[j].w, fc[i].w, acc[j][i]);
        }
    }
#pragma unroll
    for (int i = 0; i < 4; ++i) {
      unsigned tag = (((unsigned)(ch * 16 + tx)) << 4) | (unsigned)(seg * 4 + i);
#pragma unroll
      for (int j = 0; j < 4; ++j) {
        float d = fmaxf(n1q[j] + cw[i] - 2.f * acc[j][i], 0.f);
        sD[tx + 16 * i][ty + 16 * j] = packdt(d, tag);
      }
    }
    __syncthreads();
#pragma unroll
    for (int cl = 0; cl < 16; ++cl)
      PK16_INS(sD[p * 16 + cl][qq])
  }
  int pseg = seg * 4 + p;
  float* pdq = pd + ((size_t)(blockq + qq) * NSEG + pseg) * 16;
  PK16_STORE
}

// ---------------- packed merges: 16 sorted psegs -> top-16, decode global idx ----------------
template<int MODE>
__global__ __launch_bounds__(256) void k_mergepk(
    const float* __restrict__ pd, int* __restrict__ oidx)
{
  int Q = blockIdx.x * 256 + threadIdx.x;
  PK16_DECL
  for (int s = 0; s < NSEG; ++s) {
    const float* pdq = pd + ((size_t)Q * NSEG + s) * 16;
    for (int j = 0; j < 16; ++j) {
      float v = pdq[j];
      if (__all(!(v < pk15))) break;
      PK16_INS(v)
    }
  }
#define DEC(i) { unsigned u = __float_as_uint(pk##i); int m_; \
    if (MODE == 0) { unsigned ps = u & 15u, lo = (u >> 4) & 255u; \
      m_ = (int)(((ps >> 2) << 10) + ((lo >> 4) << 6) + ((ps & 3u) << 4) + (lo & 15u)); } \
    else { m_ = (int)(((u & 15u) << 8) + ((u >> 4) & 255u)); } \
    oidx[(size_t)Q * KNN + i] = m_; }
  TK16_FOREACH(DEC)
#undef DEC
}

// ---------------- fused MLP via bf16 MFMA + weightnet1 + k-sum ----------------
// 512 threads = 8 waves; each wave owns one 16-col N-tile of the 128 output
// channels. Weights converted to bf16 B-fragments ONCE per block (registers),
// amortized over PPB points. Per point: A1 = [p1|g2|dir] 16x131 bf16 in LDS ->
// 5 mfma (layer1, K=160 padded) -> h1 bf16 -> 4 mfma (layer2, K=128) ->
// multiply by weightnet (exact f32) and reduce over the 16 k-rows.
// Fragment layouts (gfx950 16x16x32 bf16): A/B: lane&15 = row/col,
// k = (lane>>4)*8 + j (contiguous); C/D (m89-verified): col=lane&15,
// row=(lane>>4)*4+reg.
#define PPB 8
__device__ ALWAYS_INLINE bf16x8 load_wfrag(const float* __restrict__ Wg,
                                           int kbase, int col, int kmax) {
  bf16x8 r;
#pragma unroll
  for (int j = 0; j < 8; ++j) {
    int k = kbase + j;
    float f = (k < kmax) ? Wg[(size_t)k * 128 + col] : 0.f;
    r[j] = (short)bf16rne(f);
  }
  return r;
}

__global__ __launch_bounds__(512) void k_mlp_mfma(
    const float* __restrict__ p1t, const float* __restrict__ p2t,
    const float* __restrict__ x1t, const float* __restrict__ x2t,
    const int* __restrict__ kidx,
    const float* __restrict__ W1, const float* __restrict__ B1v,
    const float* __restrict__ W2, const float* __restrict__ B2v,
    const float* __restrict__ wnw1, const float* __restrict__ wnb1,
    const float* __restrict__ wnw2, const float* __restrict__ wnb2,
    const float* __restrict__ wnw3, const float* __restrict__ wnb3,
    float* __restrict__ ptp)
{
  __shared__ __align__(16) unsigned short sA1[16 * 168];  // 16 rows x 160 bf16 (+8 pad)
  __shared__ __align__(16) unsigned short sH1[16 * 136];  // 16 rows x 128 bf16 (+8 pad)
  __shared__ __align__(16) float s_wv[16 * 128];
  __shared__ __align__(16) float s_c1[24];
  __shared__ __align__(16) float s_cb1[8];
  __shared__ __align__(16) float s_c2[64];
  __shared__ __align__(16) float s_cb2[8];
  __shared__ __align__(16) float s_w3[1024];
  __shared__ __align__(16) float s_b3[128];
  int tid = threadIdx.x;
  int w = tid >> 6, lane = tid & 63;
  int col = (w << 4) + (lane & 15);
  int kr0 = (lane >> 4) * 8;
  // one-time: weightnet consts -> LDS
  if (tid < 24) s_c1[tid] = wnw1[tid];
  else if (tid < 32) s_cb1[tid - 24] = wnb1[tid - 24];
  else if (tid < 96) s_c2[tid - 32] = wnw2[tid - 32];
  else if (tid < 104) s_cb2[tid - 96] = wnb2[tid - 96];
  if (tid >= 128 && tid < 256) s_b3[tid - 128] = wnb3[tid - 128];
  for (int i = tid; i < 1024; i += 512) s_w3[i] = wnw3[i];
  // one-time: weight fragments -> registers (bf16)
  bf16x8 w1f0 = load_wfrag(W1, 0 + kr0, col, 131);
  bf16x8 w1f1 = load_wfrag(W1, 32 + kr0, col, 131);
  bf16x8 w1f2 = load_wfrag(W1, 64 + kr0, col, 131);
  bf16x8 w1f3 = load_wfrag(W1, 96 + kr0, col, 131);
  bf16x8 w1f4 = load_wfrag(W1, 128 + kr0, col, 131);
  bf16x8 w2f0 = load_wfrag(W2, 0 + kr0, col, 128);
  bf16x8 w2f1 = load_wfrag(W2, 32 + kr0, col, 128);
  bf16x8 w2f2 = load_wfrag(W2, 64 + kr0, col, 128);
  bf16x8 w2f3 = load_wfrag(W2, 96 + kr0, col, 128);
  float b1c = B1v[col], b2c = B2v[col];
  int blk0 = blockIdx.x * PPB;
  int base = (blk0 >> 12) << 12;
  int r_st = tid >> 5, t_st = tid & 31;   // staging/wv: thread -> (k-row, lane-in-row)

  for (int p = 0; p < PPB; ++p) {
    int gid = blk0 + p;
    __syncthreads();   // consts ready (p=0) / prev point's s_wv,sH1 reads done
    // ---- phase 1: stage A1 (bf16) + compute weightnet wv (exact f32) ----
    {
      int m = kidx[(size_t)gid * 16 + r_st];
      int grow = base + m;
      float4 cx1 = *(const float4*)&x1t[(size_t)gid * 4];
      float4 cx2 = *(const float4*)&x2t[(size_t)grow * 4];
      unsigned short* row = &sA1[r_st * 168];
      row[t_st]      = bf16rne(p1t[(size_t)gid * 64 + t_st]);
      row[t_st + 32] = bf16rne(p1t[(size_t)gid * 64 + t_st + 32]);
      row[t_st + 64] = bf16rne(p2t[(size_t)grow * 64 + t_st]);
      row[t_st + 96] = bf16rne(p2t[(size_t)grow * 64 + t_st + 32]);
      float dx = cx2.x - cx1.x, dy = cx2.y - cx1.y, dz = cx2.z - cx1.z;
      float dv_ = (t_st == 0) ? dx : (t_st == 1) ? dy : (t_st == 2) ? dz : 0.f;
      row[t_st + 128] = bf16rne(dv_);
      // weightnet (all 32 threads of the row redundantly compute h2w, then
      // each covers 4 output channels)
      float h1w0 = fmaxf(fmaf(dz, s_c1[16], fmaf(dy, s_c1[8],  fmaf(dx, s_c1[0], s_cb1[0]))), 0.f);
      float h1w1 = fmaxf(fmaf(dz, s_c1[17], fmaf(dy, s_c1[9],  fmaf(dx, s_c1[1], s_cb1[1]))), 0.f);
      float h1w2 = fmaxf(fmaf(dz, s_c1[18], fmaf(dy, s_c1[10], fmaf(dx, s_c1[2], s_cb1[2]))), 0.f);
      float h1w3 = fmaxf(fmaf(dz, s_c1[19], fmaf(dy, s_c1[11], fmaf(dx, s_c1[3], s_cb1[3]))), 0.f);
      float h1w4 = fmaxf(fmaf(dz, s_c1[20], fmaf(dy, s_c1[12], fmaf(dx, s_c1[4], s_cb1[4]))), 0.f);
      float h1w5 = fmaxf(fmaf(dz, s_c1[21], fmaf(dy, s_c1[13], fmaf(dx, s_c1[5], s_cb1[5]))), 0.f);
      float h1w6 = fmaxf(fmaf(dz, s_c1[22], fmaf(dy, s_c1[14], fmaf(dx, s_c1[6], s_cb1[6]))), 0.f);
      float h1w7 = fmaxf(fmaf(dz, s_c1[23], fmaf(dy, s_c1[15], fmaf(dx, s_c1[7], s_cb1[7]))), 0.f);
#define H2W(j) float h2w##j; { float a_ = s_cb2[j]; \
      a_ = fmaf(h1w0, s_c2[0 * 8 + j], a_); a_ = fmaf(h1w1, s_c2[1 * 8 + j], a_); \
      a_ = fmaf(h1w2, s_c2[2 * 8 + j], a_); a_ = fmaf(h1w3, s_c2[3 * 8 + j], a_); \
      a_ = fmaf(h1w4, s_c2[4 * 8 + j], a_); a_ = fmaf(h1w5, s_c2[5 * 8 + j], a_); \
      a_ = fmaf(h1w6, s_c2[6 * 8 + j], a_); a_ = fmaf(h1w7, s_c2[7 * 8 + j], a_); \
      h2w##j = fmaxf(a_, 0.f); }
      H2W(0) H2W(1) H2W(2) H2W(3) H2W(4) H2W(5) H2W(6) H2W(7)
#undef H2W
      int c4 = t_st * 4;
      float4 wv = *(const float4*)&s_b3[c4];
#define WV(j) { float4 w3 = *(const float4*)&s_w3[j * 128 + c4]; \
      wv.x = fmaf(h2w##j, w3.x, wv.x); wv.y = fmaf(h2w##j, w3.y, wv.y); \
      wv.z = fmaf(h2w##j, w3.z, wv.z); wv.w = fmaf(h2w##j, w3.w, wv.w); }
      WV(0) WV(1) WV(2) WV(3) WV(4) WV(5) WV(6) WV(7)
#undef WV
      wv.x = fmaxf(wv.x, 0.f); wv.y = fmaxf(wv.y, 0.f);
      wv.z = fmaxf(wv.z, 0.f); wv.w = fmaxf(wv.w, 0.f);
      *(float4*)&s_wv[r_st * 128 + c4] = wv;
    }
    __syncthreads();
    // ---- phase 2: layer-1 MFMA (K=160 padded), h1 -> bf16 LDS ----
    {
      int ab = (lane & 15) * 168 + kr0;
      f32x4 acc = {0.f, 0.f, 0.f, 0.f};
      acc = __builtin_amdgcn_mfma_f32_16x16x32_bf16(*(const bf16x8*)&sA1[ab],       w1f0, acc, 0, 0, 0);
      acc = __builtin_amdgcn_mfma_f32_16x16x32_bf16(*(const bf16x8*)&sA1[ab + 32],  w1f1, acc, 0, 0, 0);
      acc = __builtin_amdgcn_mfma_f32_16x16x32_bf16(*(const bf16x8*)&sA1[ab + 64],  w1f2, acc, 0, 0, 0);
      acc = __builtin_amdgcn_mfma_f32_16x16x32_bf16(*(const bf16x8*)&sA1[ab + 96],  w1f3, acc, 0, 0, 0);
      acc = __builtin_amdgcn_mfma_f32_16x16x32_bf16(*(const bf16x8*)&sA1[ab + 128], w1f4, acc, 0, 0, 0);
      int rw0 = (lane >> 4) * 4;
#pragma unroll
      for (int r = 0; r < 4; ++r)
        sH1[(rw0 + r) * 136 + col] = bf16rne(leakyf(acc[r] + b1c));
    }
    __syncthreads();
    // ---- phase 3: layer-2 MFMA (K=128), weightnet multiply + k-reduce ----
    {
      int ab = (lane & 15) * 136 + kr0;
      f32x4 acc = {0.f, 0.f, 0.f, 0.f};
      acc = __builtin_amdgcn_mfma_f32_16x16x32_bf16(*(const bf16x8*)&sH1[ab],      w2f0, acc, 0, 0, 0);
      acc = __builtin_amdgcn_mfma_f32_16x16x32_bf16(*(const bf16x8*)&sH1[ab + 32], w2f1, acc, 0, 0, 0);
      acc = __builtin_amdgcn_mfma_f32_16x16x32_bf16(*(const bf16x8*)&sH1[ab + 64], w2f2, acc, 0, 0, 0);
      acc = __builtin_amdgcn_mfma_f32_16x16x32_bf16(*(const bf16x8*)&sH1[ab + 96], w2f3, acc, 0, 0, 0);
      int rw0 = (lane >> 4) * 4;
      float v = 0.f;
#pragma unroll
      for (int r = 0; r < 4; ++r)
        v = fmaf(s_wv[(rw0 + r) * 128 + col], leakyf(acc[r] + b2c), v);
      v += __shfl_xor(v, 16);
      v += __shfl_xor(v, 32);
      if (lane < 16) ptp[(size_t)gid * 128 + col] = v;
    }
  }
}

// ---------------- final: weightnet2 + gather + k-sum + transpose store ----------------
__global__ __launch_bounds__(256) void k_final(
    const float* __restrict__ x1t, const int* __restrict__ idx2,
    const float* __restrict__ ptp,
    const float* __restrict__ wnw1, const float* __restrict__ wnb1,
    const float* __restrict__ wnw2, const float* __restrict__ wnb2,
    const float* __restrict__ wnw3, const float* __restrict__ wnb3,
    float* __restrict__ out0)
{
  __shared__ __align__(16) float s_gc[16][128];
  __shared__ __align__(16) float s_wn[16][8];
  __shared__ __align__(16) float s_red[2][128];
  int gid = blockIdx.x, b = gid >> 12, n = gid & (NPTS - 1);
  int tid = threadIdx.x;
  if (tid < 16) {
    int m = idx2[(size_t)gid * 16 + tid];
    float4 c2 = *(const float4*)&x1t[(size_t)((b << 12) + m) * 4];
    float4 c1 = *(const float4*)&x1t[(size_t)gid * 4];
    float dx = c2.x - c1.x, dy = c2.y - c1.y, dz = c2.z - c1.z;
    float h1w[8];
#pragma unroll
    for (int j = 0; j < 8; ++j)
      h1w[j] = fmaxf(fmaf(dz, wnw1[16 + j], fmaf(dy, wnw1[8 + j], fmaf(dx, wnw1[j], wnb1[j]))), 0.f);
#pragma unroll
    for (int j = 0; j < 8; ++j) {
      float a = wnb2[j];
#pragma unroll
      for (int qq = 0; qq < 8; ++qq) a = fmaf(h1w[qq], wnw2[qq * 8 + j], a);
      s_wn[tid][j] = fmaxf(a, 0.f);
    }
  }
  int k2 = tid >> 4, i2 = tid & 15;
  int mg = idx2[(size_t)gid * 16 + k2];
  const float* src = &ptp[(size_t)((b << 12) + mg) * 128 + i2 * 8];
  *(float4*)&s_gc[k2][i2 * 8] = *(const float4*)&src[0];
  *(float4*)&s_gc[k2][i2 * 8 + 4] = *(const float4*)&src[4];
  __syncthreads();
  int ch = tid & 127, kg2 = tid >> 7;
  float r = 0.f;
#pragma unroll
  for (int jj = 0; jj < 8; ++jj) {
    int k = kg2 * 8 + jj;
    float4 wa = *(const float4*)&s_wn[k][0];
    float4 wb = *(const float4*)&s_wn[k][4];
    float wv = wnb3[ch];
    wv = fmaf(wa.x, wnw3[ch], wv);
    wv = fmaf(wa.y, wnw3[128 + ch], wv);
    wv = fmaf(wa.z, wnw3[256 + ch], wv);
    wv = fmaf(wa.w, wnw3[384 + ch], wv);
    wv = fmaf(wb.x, wnw3[512 + ch], wv);
    wv = fmaf(wb.y, wnw3[640 + ch], wv);
    wv = fmaf(wb.z, wnw3[768 + ch], wv);
    wv = fmaf(wb.w, wnw3[896 + ch], wv);
    wv = fmaxf(wv, 0.f);
    r = fmaf(wv, s_gc[k][ch], r);
  }
  s_red[kg2][ch] = r;
  __syncthreads();
  if (tid < 128)
    out0[(size_t)(b * 128 + tid) * NPTS + n] = s_red[0][tid] + s_red[1][tid];
}

extern "C" void kernel_launch(void* const* d_in, const int* in_sizes, int n_in,
                              void* d_out, int out_size, void* d_ws, size_t ws_size,
                              hipStream_t stream) {
  (void)in_sizes; (void)n_in; (void)out_size; (void)ws_size;
  const float* xyz1   = (const float*)d_in[0];
  const float* xyz2   = (const float*)d_in[1];
  const float* pts1   = (const float*)d_in[2];
  const float* pts2   = (const float*)d_in[3];
  const float* vel1   = (const float*)d_in[4];
  const float* w_xyz  = (const float*)d_in[8];
  const float* w_pts  = (const float*)d_in[10];
  const float* mlp_w1 = (const float*)d_in[11];
  const float* mlp_b1 = (const float*)d_in[12];
  const float* mlp_w2 = (const float*)d_in[13];
  const float* mlp_b2 = (const float*)d_in[14];
  const float* wn1_w1 = (const float*)d_in[15];
  const float* wn1_b1 = (const float*)d_in[16];
  const float* wn1_w2 = (const float*)d_in[17];
  const float* wn1_b2 = (const float*)d_in[18];
  const float* wn1_w3 = (const float*)d_in[19];
  const float* wn1_b3 = (const float*)d_in[20];
  const float* wn2_w1 = (const float*)d_in[21];
  const float* wn2_b1 = (const float*)d_in[22];
  const float* wn2_w2 = (const float*)d_in[23];
  const float* wn2_b2 = (const float*)d_in[24];
  const float* wn2_w3 = (const float*)d_in[25];
  const float* wn2_b3 = (const float*)d_in[26];

  char* ws = (char*)d_ws;
  size_t off = 0;
  float* pd   = (float*)(ws + off); off += (size_t)NQ * NSEG * 16 * 4;
  int*   pi   = (int*)(ws + off);   off += (size_t)NQ * NSEG * 16 * 4;
  float* f1   = (float*)(ws + off); off += (size_t)NQ * FPAD * 4;
  float* f2   = (float*)(ws + off); off += (size_t)NQ * FPAD * 4;
  float* n1   = (float*)(ws + off); off += (size_t)NQ * 4;
  float* p1t  = (float*)(ws + off); off += (size_t)NQ * DD * 4;
  float* p2t  = (float*)(ws + off); off += (size_t)NQ * DD * 4;
  float* x1t  = (float*)(ws + off); off += (size_t)NQ * 4 * 4;
  float* x2t  = (float*)(ws + off); off += (size_t)NQ * 4 * 4;
  int*   kidx = (int*)(ws + off);   off += (size_t)NQ * KNN * 4;
  float* ptp  = (float*)(ws + off); off += (size_t)NQ * 128 * 4;
  int*   idx2 = (int*)(ws + off);   off += (size_t)NQ * KNN * 4;
  float* v4   = (float*)(ws + off); off += (size_t)NQ * 4 * 4;

  float* out0 = (float*)d_out;
  float* outv = (float*)d_out + VOFF;

  k_prep<<<32, 256, 0, stream>>>(xyz1, xyz2, pts1, pts2, w_xyz, w_pts,
                                 f1, f2, n1, p1t, p2t, x1t, x2t);
  k_knn3<<<dim3(32, NSEG), 256, 0, stream>>>(x1t, pd, pi);
  k_rigid<<<32, 256, 0, stream>>>(pd, pi, x1t, vel1, outv, v4);
  k_knnf<<<dim3(128, 4), 256, 0, stream>>>(f1, f2, n1, pd);
  k_mergepk<0><<<32, 256, 0, stream>>>(pd, kidx);
  k_mlp_mfma<<<NQ / PPB, 512, 0, stream>>>(p1t, p2t, x1t, x2t, kidx,
                                           mlp_w1, mlp_b1, mlp_w2, mlp_b2,
                                           wn1_w1, wn1_b1, wn1_w2, wn1_b2,
                                           wn1_w3, wn1_b3, ptp);
  k_knnv<<<dim3(32, NSEG), 256, 0, stream>>>(v4, pd);
  k_mergepk<1><<<32, 256, 0, stream>>>(pd, idx2);
  k_final<<<NQ, 256, 0, stream>>>(x1t, idx2, ptp,
                                  wn2_w1, wn2_b1, wn2_w2, wn2_b2, wn2_w3, wn2_b3, out0);
}

// Round 9
// 380.651 us; speedup vs baseline: 1.3306x; 1.1171x over previous
//
#include <hip/hip_runtime.h>

#define NPTS 4096
#define NQ   8192      // B*N
#define DD   64
#define KNN  16
#define KC   8
#define NSEG 16
#define SEGLEN 256     // NPTS/NSEG (staged knn kernels)
#define KB96 96        // bf16 feature rows padded to 96 (67 real + 29 zeros)
#define VOFF 1048576   // B*128*N, float offset of v_world in d_out

#define ALWAYS_INLINE __attribute__((always_inline)) inline

typedef __attribute__((ext_vector_type(8))) short bf16x8;
typedef __attribute__((ext_vector_type(4))) float f32x4;

__device__ ALWAYS_INLINE float leakyf(float x) { return x > 0.f ? x : 0.1f * x; }

__device__ ALWAYS_INLINE unsigned short bf16rne(float f) {
  unsigned u = __float_as_uint(f);
  u = (u + 0x7FFFu + ((u >> 16) & 1u)) >> 16;
  return (unsigned short)u;
}

// Pack distance + 12-bit tag into one f32 sort key (d>=0 so float cmp == uint cmp).
__device__ ALWAYS_INLINE float packdt(float d, unsigned tag12) {
  return __uint_as_float((__float_as_uint(d) & 0xFFFFF000u) | tag12);
}

// ---- top-k state as NAMED SCALARS (never arrays — hipcc scratch-allocates
// per-thread arrays: rounds 1-4 measured 5-10x slowdown from this) ----
#define TK8_FOREACH(M)  M(0) M(1) M(2) M(3) M(4) M(5) M(6) M(7)
#define TK16_FOREACH(M) M(0) M(1) M(2) M(3) M(4) M(5) M(6) M(7) \
                        M(8) M(9) M(10) M(11) M(12) M(13) M(14) M(15)

#define TK_DECL1(i) float tkd##i = 3.4e38f; int tki##i = 0;
#define TK_STEP1(i) { bool c = vd < tkd##i; float t_ = tkd##i; int u_ = tki##i; \
                      tkd##i = c ? vd : tkd##i; tki##i = c ? vi : tki##i; \
                      vd = c ? t_ : vd; vi = c ? u_ : vi; }
#define TK8_DECL  TK8_FOREACH(TK_DECL1)
#define TK8_INS(dexp, mexp)  { float vd = (dexp); int vi = (mexp); \
                               if (vd < tkd7)  { TK8_FOREACH(TK_STEP1) } }

#define PK_DECL1(i) float pk##i = __uint_as_float(0x7F7FFFFFu);
#define PK_STEP1(i) { float lo_ = fminf(pk##i, pv); pv = fmaxf(pk##i, pv); pk##i = lo_; }
#define PK16_DECL    TK16_FOREACH(PK_DECL1)
#define PK16_INS(ve) { float pv = (ve); TK16_FOREACH(PK_STEP1) }
#define PK_STORE1(i) pdq[i] = pk##i;
#define PK16_STORE   TK16_FOREACH(PK_STORE1)

// ---------------- prep: transposes + bf16 feature rows + norms ----------------
__global__ __launch_bounds__(256) void k_prep(
    const float* __restrict__ xyz1, const float* __restrict__ xyz2,
    const float* __restrict__ pts1, const float* __restrict__ pts2,
    const float* __restrict__ w_xyz_p, const float* __restrict__ w_points_p,
    unsigned short* __restrict__ f1b, unsigned short* __restrict__ f2b,
    float* __restrict__ n1, float* __restrict__ n2a,
    float* __restrict__ p1t, float* __restrict__ p2t,
    float* __restrict__ x1t, float* __restrict__ x2t)
{
  int gid = blockIdx.x * 256 + threadIdx.x;   // 0..8191
  int b = gid >> 12, n = gid & (NPTS - 1);
  float wx = w_xyz_p[0], wp = w_points_p[0];
  {
    const float* xb = xyz1 + (size_t)b * 3 * NPTS;
    float x = xb[n], y = xb[NPTS + n], z = xb[2 * NPTS + n];
    float nrm2 = fmaf(z, z, fmaf(y, y, x * x));
    float4 xv; xv.x = x; xv.y = y; xv.z = z; xv.w = nrm2;
    *(float4*)&x1t[(size_t)gid * 4] = xv;
    float fx = wx * x, fy = wx * y, fz = wx * z;
    float acc = fmaf(fz, fz, fmaf(fy, fy, fx * fx));
    unsigned short* fr = f1b + (size_t)gid * KB96;
    fr[0] = bf16rne(fx); fr[1] = bf16rne(fy); fr[2] = bf16rne(fz);
    const float* pb = pts1 + (size_t)b * DD * NPTS;
    float* pr = p1t + (size_t)gid * DD;
    for (int c = 0; c < DD; ++c) {
      float v = pb[(size_t)c * NPTS + n];
      pr[c] = v;
      float fv = wp * v;
      fr[3 + c] = bf16rne(fv);
      acc = fmaf(fv, fv, acc);
    }
    for (int c = 67; c < KB96; ++c) fr[c] = 0;
    n1[gid] = acc;
  }
  {
    const float* xb = xyz2 + (size_t)b * 3 * NPTS;
    float x = xb[n], y = xb[NPTS + n], z = xb[2 * NPTS + n];
    float nrm2 = fmaf(z, z, fmaf(y, y, x * x));
    float4 xv; xv.x = x; xv.y = y; xv.z = z; xv.w = nrm2;
    *(float4*)&x2t[(size_t)gid * 4] = xv;
    float fx = wx * x, fy = wx * y, fz = wx * z;
    float acc = fmaf(fz, fz, fmaf(fy, fy, fx * fx));
    unsigned short* fr = f2b + (size_t)gid * KB96;
    fr[0] = bf16rne(fx); fr[1] = bf16rne(fy); fr[2] = bf16rne(fz);
    const float* pb = pts2 + (size_t)b * DD * NPTS;
    float* pr = p2t + (size_t)gid * DD;
    for (int c = 0; c < DD; ++c) {
      float v = pb[(size_t)c * NPTS + n];
      pr[c] = v;
      float fv = wp * v;
      fr[3 + c] = bf16rne(fv);
      acc = fmaf(fv, fv, acc);
    }
    for (int c = 67; c < KB96; ++c) fr[c] = 0;
    n2a[gid] = acc;
  }
}

// ------- knn over xyz1 (LDS-staged), K=8, EXACT (feeds rigid regression) -------
__global__ __launch_bounds__(256) void k_knn3(
    const float* __restrict__ x4, float* __restrict__ pd, int* __restrict__ pi)
{
  __shared__ __align__(16) float4 sc[128];
  int seg = blockIdx.y;
  int Q = blockIdx.x * 256 + threadIdx.x;
  int b = Q >> 12;
  float4 q = *(const float4*)&x4[(size_t)Q * 4];
  TK8_DECL
  int gbase = (b << 12) + seg * SEGLEN;
  for (int ch = 0; ch < SEGLEN / 128; ++ch) {
    __syncthreads();
    if (threadIdx.x < 128)
      sc[threadIdx.x] = *(const float4*)&x4[(size_t)(gbase + ch * 128 + threadIdx.x) * 4];
    __syncthreads();
    int m0 = seg * SEGLEN + ch * 128;
    for (int j = 0; j < 128; ++j) {
      float4 c = sc[j];
      float dot = fmaf(q.z, c.z, fmaf(q.y, c.y, q.x * c.x));
      float d = fmaxf(q.w + c.w - 2.f * dot, 0.f);
      TK8_INS(d, m0 + j)
    }
  }
  float* pdq = pd + ((size_t)Q * NSEG + seg) * 16;
  int* piq = pi + ((size_t)Q * NSEG + seg) * 16;
#define ST8(i) pdq[i] = tkd##i; piq[i] = tki##i;
  TK8_FOREACH(ST8)
#undef ST8
}

// ------- knn over v_world (LDS-staged), K=16, packed keys -------
__global__ __launch_bounds__(256) void k_knnv(
    const float* __restrict__ x4, float* __restrict__ pd)
{
  __shared__ __align__(16) float4 sc[128];
  int seg = blockIdx.y;
  int Q = blockIdx.x * 256 + threadIdx.x;
  int b = Q >> 12;
  float4 q = *(const float4*)&x4[(size_t)Q * 4];
  PK16_DECL
  int gbase = (b << 12) + seg * SEGLEN;
  for (int ch = 0; ch < SEGLEN / 128; ++ch) {
    __syncthreads();
    if (threadIdx.x < 128)
      sc[threadIdx.x] = *(const float4*)&x4[(size_t)(gbase + ch * 128 + threadIdx.x) * 4];
    __syncthreads();
    unsigned base_tag = ((unsigned)ch << 11) | (unsigned)seg;
#pragma unroll
    for (int j = 0; j < 128; ++j) {
      float4 c = sc[j];
      float dot = fmaf(q.z, c.z, fmaf(q.y, c.y, q.x * c.x));
      float d = fmaxf(q.w + c.w - 2.f * dot, 0.f);
      PK16_INS(packdt(d, base_tag | ((unsigned)j << 4)))
    }
  }
  float* pdq = pd + ((size_t)Q * NSEG + seg) * 16;
  PK16_STORE
}

// ---------------- merge K=8 + rigid velocity regression (+ padded v4 out) ----------------
__global__ __launch_bounds__(256) void k_rigid(
    const float* __restrict__ pd, const int* __restrict__ pi,
    const float* __restrict__ x4, const float* __restrict__ vel1,
    float* __restrict__ vout, float* __restrict__ v4out)
{
  int Q = blockIdx.x * 256 + threadIdx.x;
  int b = Q >> 12;
  TK8_DECL
  for (int s = 0; s < NSEG; ++s) {
    const float* pdq = pd + ((size_t)Q * NSEG + s) * 16;
    const int* piq = pi + ((size_t)Q * NSEG + s) * 16;
#pragma unroll
    for (int j = 0; j < KC; ++j) TK8_INS(pdq[j], piq[j])
  }
  int base = b << 12;
  double a00 = 0, a01 = 0, a02 = 0, a11 = 0, a12 = 0, a22 = 0;
  double r0 = 0, r1 = 0, r2 = 0;
#define RIG_ACC(i) { \
    float4 c = *(const float4*)&x4[(size_t)(base + tki##i) * 4]; \
    float nr = sqrtf(c.w); \
    float ux = c.x / nr, uy = c.y / nr, uz = c.z / nr; \
    float cv = vel1[base + tki##i]; \
    double dx = ux, dy = uy, dz = uz, dvv = cv; \
    a00 += dx * dx; a01 += dx * dy; a02 += dx * dz; \
    a11 += dy * dy; a12 += dy * dz; a22 += dz * dz; \
    r0 += dx * dvv; r1 += dy * dvv; r2 += dz * dvv; }
  TK8_FOREACH(RIG_ACC)
#undef RIG_ACC
  a00 += 1e-6; a11 += 1e-6; a22 += 1e-6;
  double c00 = a11 * a22 - a12 * a12;
  double c01 = a02 * a12 - a01 * a22;
  double c02 = a01 * a12 - a02 * a11;
  double c11 = a00 * a22 - a02 * a02;
  double c12 = a02 * a01 - a00 * a12;
  double c22 = a00 * a11 - a01 * a01;
  double det = a00 * c00 + a01 * c01 + a02 * c02;
  double inv = 1.0 / det;
  float vx = (float)((c00 * r0 + c01 * r1 + c02 * r2) * inv);
  float vy = (float)((c01 * r0 + c11 * r1 + c12 * r2) * inv);
  float vz = (float)((c02 * r0 + c12 * r1 + c22 * r2) * inv);
  vout[(size_t)Q * 3 + 0] = vx;
  vout[(size_t)Q * 3 + 1] = vy;
  vout[(size_t)Q * 3 + 2] = vz;
  float4 v; v.x = vx; v.y = vy; v.z = vz;
  v.w = fmaf(vz, vz, fmaf(vy, vy, vx * vx));
  *(float4*)&v4out[(size_t)Q * 4] = v;
}

// ------- knnf via bf16 MFMA: 16 queries x 1024 candidates per block -------
// 4 waves; wave w owns candidate cols [w*16, w*16+16) of each 64-cand chunk.
// A-fragments (query features) hoisted into registers for the whole block.
// D tile -> packed keys in sD -> existing per-stream PK16 top-k (threads 0-63).
// Fragment layouts (validated by k_mlp_mfma, m89): A/B: lane&15 = row/col,
// k=(lane>>4)*8+j contiguous; C/D: col=lane&15, row=(lane>>4)*4+reg.
__global__ __launch_bounds__(256) void k_knnf_mfma(
    const unsigned short* __restrict__ f1b, const unsigned short* __restrict__ f2b,
    const float* __restrict__ n1, const float* __restrict__ n2a,
    float* __restrict__ pd)
{
  __shared__ __align__(16) unsigned short sf1[16 * KB96];   // 3 KB
  __shared__ __align__(16) unsigned short sf2[64 * KB96];   // 12 KB
  __shared__ __align__(16) float sn1[16];
  __shared__ __align__(16) float sn2[64];
  __shared__ __align__(16) float sD[64][21];                // packed keys, pad 21
  int tid = threadIdx.x;
  int w = tid >> 6, lane = tid & 63;
  int i15 = lane & 15, g = lane >> 4, kr0 = g * 8;
  int blockq = blockIdx.x * 16;
  int b = blockq >> 12;
  int seg = blockIdx.y;
  int gbase = (b << 12) + seg * 1024;
  {
    const float4* src = (const float4*)(f1b + (size_t)blockq * KB96);
    if (tid < 192) ((float4*)sf1)[tid] = src[tid];
    if (tid < 16) sn1[tid] = n1[blockq + tid];
  }
  __syncthreads();
  // A-fragments: rows = 16 queries, 3 K-steps of 32 (K padded to 96 with zeros)
  bf16x8 af0 = *(const bf16x8*)&sf1[i15 * KB96 + kr0];
  bf16x8 af1 = *(const bf16x8*)&sf1[i15 * KB96 + 32 + kr0];
  bf16x8 af2 = *(const bf16x8*)&sf1[i15 * KB96 + 64 + kr0];
  float nq0 = sn1[g * 4 + 0], nq1 = sn1[g * 4 + 1];
  float nq2 = sn1[g * 4 + 2], nq3 = sn1[g * 4 + 3];
  PK16_DECL
  int q_tk = tid & 15, p_tk = tid >> 4;   // top-k mapping (threads 0-63)
  for (int ch = 0; ch < 16; ++ch) {
    __syncthreads();   // sD consumed by prev top-k / first iter no-op
    {
      const float4* src = (const float4*)(f2b + (size_t)(gbase + ch * 64) * KB96);
      ((float4*)sf2)[tid] = src[tid];
      ((float4*)sf2)[tid + 256] = src[tid + 256];
      ((float4*)sf2)[tid + 512] = src[tid + 512];
      if (tid < 64) sn2[tid] = n2a[gbase + ch * 64 + tid];
    }
    __syncthreads();   // sf2/sn2 ready
    {
      int crow = w * 16 + i15;
      const unsigned short* c_ = &sf2[crow * KB96 + kr0];
      f32x4 acc = {0.f, 0.f, 0.f, 0.f};
      acc = __builtin_amdgcn_mfma_f32_16x16x32_bf16(af0, *(const bf16x8*)&c_[0],  acc, 0, 0, 0);
      acc = __builtin_amdgcn_mfma_f32_16x16x32_bf16(af1, *(const bf16x8*)&c_[32], acc, 0, 0, 0);
      acc = __builtin_amdgcn_mfma_f32_16x16x32_bf16(af2, *(const bf16x8*)&c_[64], acc, 0, 0, 0);
      float nn2 = sn2[crow];
      unsigned tag = (((unsigned)(ch * 16 + i15)) << 4) | (unsigned)(seg * 4 + w);
      sD[crow][g * 4 + 0] = packdt(fmaxf(nq0 + nn2 - 2.f * acc[0], 0.f), tag);
      sD[crow][g * 4 + 1] = packdt(fmaxf(nq1 + nn2 - 2.f * acc[1], 0.f), tag);
      sD[crow][g * 4 + 2] = packdt(fmaxf(nq2 + nn2 - 2.f * acc[2], 0.f), tag);
      sD[crow][g * 4 + 3] = packdt(fmaxf(nq3 + nn2 - 2.f * acc[3], 0.f), tag);
    }
    __syncthreads();   // sD ready
    if (tid < 64) {
#pragma unroll
      for (int cl = 0; cl < 16; ++cl)
        PK16_INS(sD[p_tk * 16 + cl][q_tk])
    }
  }
  if (tid < 64) {
    int pseg = seg * 4 + p_tk;
    float* pdq = pd + ((size_t)(blockq + q_tk) * NSEG + pseg) * 16;
    PK16_STORE
  }
}

// ---------------- packed merges: 16 sorted psegs -> top-16, decode global idx ----------------
template<int MODE>
__global__ __launch_bounds__(256) void k_mergepk(
    const float* __restrict__ pd, int* __restrict__ oidx)
{
  int Q = blockIdx.x * 256 + threadIdx.x;
  PK16_DECL
  for (int s = 0; s < NSEG; ++s) {
    const float* pdq = pd + ((size_t)Q * NSEG + s) * 16;
    for (int j = 0; j < 16; ++j) {
      float v = pdq[j];
      if (__all(!(v < pk15))) break;
      PK16_INS(v)
    }
  }
#define DEC(i) { unsigned u = __float_as_uint(pk##i); int m_; \
    if (MODE == 0) { unsigned ps = u & 15u, lo = (u >> 4) & 255u; \
      m_ = (int)(((ps >> 2) << 10) + ((lo >> 4) << 6) + ((ps & 3u) << 4) + (lo & 15u)); } \
    else { m_ = (int)(((u & 15u) << 8) + ((u >> 4) & 255u)); } \
    oidx[(size_t)Q * KNN + i] = m_; }
  TK16_FOREACH(DEC)
#undef DEC
}

// ---------------- fused MLP via bf16 MFMA + weightnet1 + k-sum ----------------
#define PPB 8
__device__ ALWAYS_INLINE bf16x8 load_wfrag(const float* __restrict__ Wg,
                                           int kbase, int col, int kmax) {
  bf16x8 r;
#pragma unroll
  for (int j = 0; j < 8; ++j) {
    int k = kbase + j;
    float f = (k < kmax) ? Wg[(size_t)k * 128 + col] : 0.f;
    r[j] = (short)bf16rne(f);
  }
  return r;
}

__global__ __launch_bounds__(512) void k_mlp_mfma(
    const float* __restrict__ p1t, const float* __restrict__ p2t,
    const float* __restrict__ x1t, const float* __restrict__ x2t,
    const int* __restrict__ kidx,
    const float* __restrict__ W1, const float* __restrict__ B1v,
    const float* __restrict__ W2, const float* __restrict__ B2v,
    const float* __restrict__ wnw1, const float* __restrict__ wnb1,
    const float* __restrict__ wnw2, const float* __restrict__ wnb2,
    const float* __restrict__ wnw3, const float* __restrict__ wnb3,
    float* __restrict__ ptp)
{
  __shared__ __align__(16) unsigned short sA1[16 * 168];
  __shared__ __align__(16) unsigned short sH1[16 * 136];
  __shared__ __align__(16) float s_wv[16 * 128];
  __shared__ __align__(16) float s_c1[24];
  __shared__ __align__(16) float s_cb1[8];
  __shared__ __align__(16) float s_c2[64];
  __shared__ __align__(16) float s_cb2[8];
  __shared__ __align__(16) float s_w3[1024];
  __shared__ __align__(16) float s_b3[128];
  int tid = threadIdx.x;
  int w = tid >> 6, lane = tid & 63;
  int col = (w << 4) + (lane & 15);
  int kr0 = (lane >> 4) * 8;
  if (tid < 24) s_c1[tid] = wnw1[tid];
  else if (tid < 32) s_cb1[tid - 24] = wnb1[tid - 24];
  else if (tid < 96) s_c2[tid - 32] = wnw2[tid - 32];
  else if (tid < 104) s_cb2[tid - 96] = wnb2[tid - 96];
  if (tid >= 128 && tid < 256) s_b3[tid - 128] = wnb3[tid - 128];
  for (int i = tid; i < 1024; i += 512) s_w3[i] = wnw3[i];
  bf16x8 w1f0 = load_wfrag(W1, 0 + kr0, col, 131);
  bf16x8 w1f1 = load_wfrag(W1, 32 + kr0, col, 131);
  bf16x8 w1f2 = load_wfrag(W1, 64 + kr0, col, 131);
  bf16x8 w1f3 = load_wfrag(W1, 96 + kr0, col, 131);
  bf16x8 w1f4 = load_wfrag(W1, 128 + kr0, col, 131);
  bf16x8 w2f0 = load_wfrag(W2, 0 + kr0, col, 128);
  bf16x8 w2f1 = load_wfrag(W2, 32 + kr0, col, 128);
  bf16x8 w2f2 = load_wfrag(W2, 64 + kr0, col, 128);
  bf16x8 w2f3 = load_wfrag(W2, 96 + kr0, col, 128);
  float b1c = B1v[col], b2c = B2v[col];
  int blk0 = blockIdx.x * PPB;
  int base = (blk0 >> 12) << 12;
  int r_st = tid >> 5, t_st = tid & 31;

  for (int p = 0; p < PPB; ++p) {
    int gid = blk0 + p;
    __syncthreads();
    {
      int m = kidx[(size_t)gid * 16 + r_st];
      int grow = base + m;
      float4 cx1 = *(const float4*)&x1t[(size_t)gid * 4];
      float4 cx2 = *(const float4*)&x2t[(size_t)grow * 4];
      unsigned short* row = &sA1[r_st * 168];
      row[t_st]      = bf16rne(p1t[(size_t)gid * 64 + t_st]);
      row[t_st + 32] = bf16rne(p1t[(size_t)gid * 64 + t_st + 32]);
      row[t_st + 64] = bf16rne(p2t[(size_t)grow * 64 + t_st]);
      row[t_st + 96] = bf16rne(p2t[(size_t)grow * 64 + t_st + 32]);
      float dx = cx2.x - cx1.x, dy = cx2.y - cx1.y, dz = cx2.z - cx1.z;
      float dv_ = (t_st == 0) ? dx : (t_st == 1) ? dy : (t_st == 2) ? dz : 0.f;
      row[t_st + 128] = bf16rne(dv_);
      float h1w0 = fmaxf(fmaf(dz, s_c1[16], fmaf(dy, s_c1[8],  fmaf(dx, s_c1[0], s_cb1[0]))), 0.f);
      float h1w1 = fmaxf(fmaf(dz, s_c1[17], fmaf(dy, s_c1[9],  fmaf(dx, s_c1[1], s_cb1[1]))), 0.f);
      float h1w2 = fmaxf(fmaf(dz, s_c1[18], fmaf(dy, s_c1[10], fmaf(dx, s_c1[2], s_cb1[2]))), 0.f);
      float h1w3 = fmaxf(fmaf(dz, s_c1[19], fmaf(dy, s_c1[11], fmaf(dx, s_c1[3], s_cb1[3]))), 0.f);
      float h1w4 = fmaxf(fmaf(dz, s_c1[20], fmaf(dy, s_c1[12], fmaf(dx, s_c1[4], s_cb1[4]))), 0.f);
      float h1w5 = fmaxf(fmaf(dz, s_c1[21], fmaf(dy, s_c1[13], fmaf(dx, s_c1[5], s_cb1[5]))), 0.f);
      float h1w6 = fmaxf(fmaf(dz, s_c1[22], fmaf(dy, s_c1[14], fmaf(dx, s_c1[6], s_cb1[6]))), 0.f);
      float h1w7 = fmaxf(fmaf(dz, s_c1[23], fmaf(dy, s_c1[15], fmaf(dx, s_c1[7], s_cb1[7]))), 0.f);
#define H2W(j) float h2w##j; { float a_ = s_cb2[j]; \
      a_ = fmaf(h1w0, s_c2[0 * 8 + j], a_); a_ = fmaf(h1w1, s_c2[1 * 8 + j], a_); \
      a_ = fmaf(h1w2, s_c2[2 * 8 + j], a_); a_ = fmaf(h1w3, s_c2[3 * 8 + j], a_); \
      a_ = fmaf(h1w4, s_c2[4 * 8 + j], a_); a_ = fmaf(h1w5, s_c2[5 * 8 + j], a_); \
      a_ = fmaf(h1w6, s_c2[6 * 8 + j], a_); a_ = fmaf(h1w7, s_c2[7 * 8 + j], a_); \
      h2w##j = fmaxf(a_, 0.f); }
      H2W(0) H2W(1) H2W(2) H2W(3) H2W(4) H2W(5) H2W(6) H2W(7)
#undef H2W
      int c4 = t_st * 4;
      float4 wv = *(const float4*)&s_b3[c4];
#define WV(j) { float4 w3 = *(const float4*)&s_w3[j * 128 + c4]; \
      wv.x = fmaf(h2w##j, w3.x, wv.x); wv.y = fmaf(h2w##j, w3.y, wv.y); \
      wv.z = fmaf(h2w##j, w3.z, wv.z); wv.w = fmaf(h2w##j, w3.w, wv.w); }
      WV(0) WV(1) WV(2) WV(3) WV(4) WV(5) WV(6) WV(7)
#undef WV
      wv.x = fmaxf(wv.x, 0.f); wv.y = fmaxf(wv.y, 0.f);
      wv.z = fmaxf(wv.z, 0.f); wv.w = fmaxf(wv.w, 0.f);
      *(float4*)&s_wv[r_st * 128 + c4] = wv;
    }
    __syncthreads();
    {
      int ab = (lane & 15) * 168 + kr0;
      f32x4 acc = {0.f, 0.f, 0.f, 0.f};
      acc = __builtin_amdgcn_mfma_f32_16x16x32_bf16(*(const bf16x8*)&sA1[ab],       w1f0, acc, 0, 0, 0);
      acc = __builtin_amdgcn_mfma_f32_16x16x32_bf16(*(const bf16x8*)&sA1[ab + 32],  w1f1, acc, 0, 0, 0);
      acc = __builtin_amdgcn_mfma_f32_16x16x32_bf16(*(const bf16x8*)&sA1[ab + 64],  w1f2, acc, 0, 0, 0);
      acc = __builtin_amdgcn_mfma_f32_16x16x32_bf16(*(const bf16x8*)&sA1[ab + 96],  w1f3, acc, 0, 0, 0);
      acc = __builtin_amdgcn_mfma_f32_16x16x32_bf16(*(const bf16x8*)&sA1[ab + 128], w1f4, acc, 0, 0, 0);
      int rw0 = (lane >> 4) * 4;
#pragma unroll
      for (int r = 0; r < 4; ++r)
        sH1[(rw0 + r) * 136 + col] = bf16rne(leakyf(acc[r] + b1c));
    }
    __syncthreads();
    {
      int ab = (lane & 15) * 136 + kr0;
      f32x4 acc = {0.f, 0.f, 0.f, 0.f};
      acc = __builtin_amdgcn_mfma_f32_16x16x32_bf16(*(const bf16x8*)&sH1[ab],      w2f0, acc, 0, 0, 0);
      acc = __builtin_amdgcn_mfma_f32_16x16x32_bf16(*(const bf16x8*)&sH1[ab + 32], w2f1, acc, 0, 0, 0);
      acc = __builtin_amdgcn_mfma_f32_16x16x32_bf16(*(const bf16x8*)&sH1[ab + 64], w2f2, acc, 0, 0, 0);
      acc = __builtin_amdgcn_mfma_f32_16x16x32_bf16(*(const bf16x8*)&sH1[ab + 96], w2f3, acc, 0, 0, 0);
      int rw0 = (lane >> 4) * 4;
      float v = 0.f;
#pragma unroll
      for (int r = 0; r < 4; ++r)
        v = fmaf(s_wv[(rw0 + r) * 128 + col], leakyf(acc[r] + b2c), v);
      v += __shfl_xor(v, 16);
      v += __shfl_xor(v, 32);
      if (lane < 16) ptp[(size_t)gid * 128 + col] = v;
    }
  }
}

// ---------------- final: weightnet2 + gather + k-sum + transpose store ----------------
__global__ __launch_bounds__(256) void k_final(
    const float* __restrict__ x1t, const int* __restrict__ idx2,
    const float* __restrict__ ptp,
    const float* __restrict__ wnw1, const float* __restrict__ wnb1,
    const float* __restrict__ wnw2, const float* __restrict__ wnb2,
    const float* __restrict__ wnw3, const float* __restrict__ wnb3,
    float* __restrict__ out0)
{
  __shared__ __align__(16) float s_gc[16][128];
  __shared__ __align__(16) float s_wn[16][8];
  __shared__ __align__(16) float s_red[2][128];
  int gid = blockIdx.x, b = gid >> 12, n = gid & (NPTS - 1);
  int tid = threadIdx.x;
  if (tid < 16) {
    int m = idx2[(size_t)gid * 16 + tid];
    float4 c2 = *(const float4*)&x1t[(size_t)((b << 12) + m) * 4];
    float4 c1 = *(const float4*)&x1t[(size_t)gid * 4];
    float dx = c2.x - c1.x, dy = c2.y - c1.y, dz = c2.z - c1.z;
    float h1w[8];
#pragma unroll
    for (int j = 0; j < 8; ++j)
      h1w[j] = fmaxf(fmaf(dz, wnw1[16 + j], fmaf(dy, wnw1[8 + j], fmaf(dx, wnw1[j], wnb1[j]))), 0.f);
#pragma unroll
    for (int j = 0; j < 8; ++j) {
      float a = wnb2[j];
#pragma unroll
      for (int qq = 0; qq < 8; ++qq) a = fmaf(h1w[qq], wnw2[qq * 8 + j], a);
      s_wn[tid][j] = fmaxf(a, 0.f);
    }
  }
  int k2 = tid >> 4, i2 = tid & 15;
  int mg = idx2[(size_t)gid * 16 + k2];
  const float* src = &ptp[(size_t)((b << 12) + mg) * 128 + i2 * 8];
  *(float4*)&s_gc[k2][i2 * 8] = *(const float4*)&src[0];
  *(float4*)&s_gc[k2][i2 * 8 + 4] = *(const float4*)&src[4];
  __syncthreads();
  int ch = tid & 127, kg2 = tid >> 7;
  float r = 0.f;
#pragma unroll
  for (int jj = 0; jj < 8; ++jj) {
    int k = kg2 * 8 + jj;
    float4 wa = *(const float4*)&s_wn[k][0];
    float4 wb = *(const float4*)&s_wn[k][4];
    float wv = wnb3[ch];
    wv = fmaf(wa.x, wnw3[ch], wv);
    wv = fmaf(wa.y, wnw3[128 + ch], wv);
    wv = fmaf(wa.z, wnw3[256 + ch], wv);
    wv = fmaf(wa.w, wnw3[384 + ch], wv);
    wv = fmaf(wb.x, wnw3[512 + ch], wv);
    wv = fmaf(wb.y, wnw3[640 + ch], wv);
    wv = fmaf(wb.z, wnw3[768 + ch], wv);
    wv = fmaf(wb.w, wnw3[896 + ch], wv);
    wv = fmaxf(wv, 0.f);
    r = fmaf(wv, s_gc[k][ch], r);
  }
  s_red[kg2][ch] = r;
  __syncthreads();
  if (tid < 128)
    out0[(size_t)(b * 128 + tid) * NPTS + n] = s_red[0][tid] + s_red[1][tid];
}

extern "C" void kernel_launch(void* const* d_in, const int* in_sizes, int n_in,
                              void* d_out, int out_size, void* d_ws, size_t ws_size,
                              hipStream_t stream) {
  (void)in_sizes; (void)n_in; (void)out_size; (void)ws_size;
  const float* xyz1   = (const float*)d_in[0];
  const float* xyz2   = (const float*)d_in[1];
  const float* pts1   = (const float*)d_in[2];
  const float* pts2   = (const float*)d_in[3];
  const float* vel1   = (const float*)d_in[4];
  const float* w_xyz  = (const float*)d_in[8];
  const float* w_pts  = (const float*)d_in[10];
  const float* mlp_w1 = (const float*)d_in[11];
  const float* mlp_b1 = (const float*)d_in[12];
  const float* mlp_w2 = (const float*)d_in[13];
  const float* mlp_b2 = (const float*)d_in[14];
  const float* wn1_w1 = (const float*)d_in[15];
  const float* wn1_b1 = (const float*)d_in[16];
  const float* wn1_w2 = (const float*)d_in[17];
  const float* wn1_b2 = (const float*)d_in[18];
  const float* wn1_w3 = (const float*)d_in[19];
  const float* wn1_b3 = (const float*)d_in[20];
  const float* wn2_w1 = (const float*)d_in[21];
  const float* wn2_b1 = (const float*)d_in[22];
  const float* wn2_w2 = (const float*)d_in[23];
  const float* wn2_b2 = (const float*)d_in[24];
  const float* wn2_w3 = (const float*)d_in[25];
  const float* wn2_b3 = (const float*)d_in[26];

  char* ws = (char*)d_ws;
  size_t off = 0;
  float* pd   = (float*)(ws + off); off += (size_t)NQ * NSEG * 16 * 4;   // 8 MB
  int*   pi   = (int*)(ws + off);   off += (size_t)NQ * NSEG * 16 * 4;   // 8 MB
  unsigned short* f1b = (unsigned short*)(ws + off); off += (size_t)NQ * KB96 * 2;
  unsigned short* f2b = (unsigned short*)(ws + off); off += (size_t)NQ * KB96 * 2;
  float* n1   = (float*)(ws + off); off += (size_t)NQ * 4;
  float* n2a  = (float*)(ws + off); off += (size_t)NQ * 4;
  float* p1t  = (float*)(ws + off); off += (size_t)NQ * DD * 4;
  float* p2t  = (float*)(ws + off); off += (size_t)NQ * DD * 4;
  float* x1t  = (float*)(ws + off); off += (size_t)NQ * 4 * 4;
  float* x2t  = (float*)(ws + off); off += (size_t)NQ * 4 * 4;
  int*   kidx = (int*)(ws + off);   off += (size_t)NQ * KNN * 4;
  float* ptp  = (float*)(ws + off); off += (size_t)NQ * 128 * 4;
  int*   idx2 = (int*)(ws + off);   off += (size_t)NQ * KNN * 4;
  float* v4   = (float*)(ws + off); off += (size_t)NQ * 4 * 4;

  float* out0 = (float*)d_out;
  float* outv = (float*)d_out + VOFF;

  k_prep<<<32, 256, 0, stream>>>(xyz1, xyz2, pts1, pts2, w_xyz, w_pts,
                                 f1b, f2b, n1, n2a, p1t, p2t, x1t, x2t);
  k_knn3<<<dim3(32, NSEG), 256, 0, stream>>>(x1t, pd, pi);
  k_rigid<<<32, 256, 0, stream>>>(pd, pi, x1t, vel1, outv, v4);
  k_knnf_mfma<<<dim3(NQ / 16, 4), 256, 0, stream>>>(f1b, f2b, n1, n2a, pd);
  k_mergepk<0><<<32, 256, 0, stream>>>(pd, kidx);
  k_mlp_mfma<<<NQ / PPB, 512, 0, stream>>>(p1t, p2t, x1t, x2t, kidx,
                                           mlp_w1, mlp_b1, mlp_w2, mlp_b2,
                                           wn1_w1, wn1_b1, wn1_w2, wn1_b2,
                                           wn1_w3, wn1_b3, ptp);
  k_knnv<<<dim3(32, NSEG), 256, 0, stream>>>(v4, pd);
  k_mergepk<1><<<32, 256, 0, stream>>>(pd, idx2);
  k_final<<<NQ, 256, 0, stream>>>(x1t, idx2, ptp,
                                  wn2_w1, wn2_b1, wn2_w2, wn2_b2, wn2_w3, wn2_b3, out0);
}